// Round 1
// baseline (29319.040 us; speedup 1.0000x reference)
//
#include <hip/hip_runtime.h>
#include <hip/hip_bf16.h>

#define DEV __device__ __forceinline__

DEV float loadf(const float* p, int i) { return p[i]; }
DEV float loadf(const __hip_bfloat16* p, int i) { return __bfloat162float(p[i]); }
DEV void storef(float* p, int i, float v) { p[i] = v; }
DEV void storef(__hip_bfloat16* p, int i, float v) { p[i] = __float2bfloat16(v); }

DEV float gelu_erf(float x) { return 0.5f * x * (1.0f + erff(x * 0.70710678118654752440f)); }

// Generic direct conv: block = (b, oc); threads loop over OH*OW.
// Weights for this oc staged in LDS. Optional fused eval-BN + exact GELU.
template <typename InT, typename OutT, bool BNG, int KH, int KW>
__global__ void conv_k(const InT* __restrict__ in, const float* __restrict__ w,
                       const float* __restrict__ gamma, const float* __restrict__ beta,
                       OutT* __restrict__ out,
                       int B, int IC, int IH, int IW,
                       int OC, int OH, int OW,
                       int SH, int SW, int PH, int PW)
{
    extern __shared__ float lw[];
    const int oc = blockIdx.x % OC;
    const int b  = blockIdx.x / OC;
    const int kelem = IC * KH * KW;
    for (int i = threadIdx.x; i < kelem; i += blockDim.x)
        lw[i] = w[(size_t)oc * kelem + i];
    __syncthreads();

    float s = 1.f, bb = 0.f;
    if (BNG) { s = gamma[oc] * rsqrtf(1.0f + 1e-5f); bb = beta[oc]; }

    const int npos = OH * OW;
    const InT* inb = in + (size_t)b * IC * IH * IW;
    OutT* outb = out + ((size_t)b * OC + oc) * (size_t)npos;

    for (int pos = threadIdx.x; pos < npos; pos += blockDim.x) {
        const int oh = pos / OW, ow = pos - oh * OW;
        const int ih0 = oh * SH - PH, iw0 = ow * SW - PW;
        float acc = 0.f;
        if (ih0 >= 0 && iw0 >= 0 && ih0 + KH <= IH && iw0 + KW <= IW) {
            // interior: fully unrolled
            const InT* ip = inb + (size_t)ih0 * IW + iw0;
            const float* wp = lw;
            for (int ic = 0; ic < IC; ++ic) {
#pragma unroll
                for (int kh = 0; kh < KH; ++kh) {
                    const InT* ipr = ip + kh * IW;
                    const float* wpr = wp + kh * KW;
#pragma unroll
                    for (int kw = 0; kw < KW; ++kw)
                        acc += loadf(ipr, kw) * wpr[kw];
                }
                ip += (size_t)IH * IW;
                wp += KH * KW;
            }
        } else {
            // edge: clamped kernel ranges
            const int khl = ih0 < 0 ? -ih0 : 0;
            const int khh = (IH - ih0) < KH ? (IH - ih0) : KH;
            const int kwl = iw0 < 0 ? -iw0 : 0;
            const int kwh = (IW - iw0) < KW ? (IW - iw0) : KW;
            for (int ic = 0; ic < IC; ++ic) {
                const InT* ip = inb + ((size_t)ic * IH + ih0) * IW + iw0;
                const float* wp = lw + ic * KH * KW;
                for (int kh = khl; kh < khh; ++kh) {
                    const InT* ipr = ip + kh * IW;
                    const float* wpr = wp + kh * KW;
                    for (int kw = kwl; kw < kwh; ++kw)
                        acc += loadf(ipr, kw) * wpr[kw];
                }
            }
        }
        float y = acc * s + bb;
        if (BNG) y = gelu_erf(y);
        storef(outb, pos, y);
    }
}

// Per-batch: mean-pool [256,5,5] -> FC1(256->32)+GELU+BN1d -> FC2(32->5) -> logits + top-2 (sorted).
__global__ void route_k(const float* __restrict__ h4,
                        const float* __restrict__ fw1, const float* __restrict__ fb1,
                        const float* __restrict__ g1d, const float* __restrict__ b1d,
                        const float* __restrict__ fw2, const float* __restrict__ fb2,
                        float* __restrict__ rw_out, int* __restrict__ sel_out)
{
    __shared__ float pooled[256];
    __shared__ float hmid[32];
    __shared__ float rwv[5];
    const int b = blockIdx.x, c = threadIdx.x;
    const float* p = h4 + ((size_t)b * 256 + c) * 25;
    float sum = 0.f;
#pragma unroll
    for (int i = 0; i < 25; ++i) sum += p[i];
    pooled[c] = sum * (1.0f / 25.0f);
    __syncthreads();
    if (c < 32) {
        float a = fb1[c];
        const float* wr = fw1 + c * 256;
        for (int i = 0; i < 256; ++i) a += pooled[i] * wr[i];
        a = gelu_erf(a);
        a = a * (g1d[c] * rsqrtf(1.0f + 1e-5f)) + b1d[c];
        hmid[c] = a;
    }
    __syncthreads();
    if (c < 5) {
        float a = fb2[c];
        const float* wr = fw2 + c * 32;
#pragma unroll
        for (int i = 0; i < 32; ++i) a += hmid[i] * wr[i];
        rwv[c] = a;
        rw_out[b * 5 + c] = a;
    }
    __syncthreads();
    if (c == 0) {
        // top-2 with first-index tie-break (matches jax.lax.top_k), then ascending sort
        int i1 = 0;
        for (int i = 1; i < 5; ++i) if (rwv[i] > rwv[i1]) i1 = i;
        int i2 = -1;
        for (int i = 0; i < 5; ++i) {
            if (i == i1) continue;
            if (i2 < 0 || rwv[i] > rwv[i2]) i2 = i;
        }
        sel_out[b * 2]     = i1 < i2 ? i1 : i2;
        sel_out[b * 2 + 1] = i1 < i2 ? i2 : i1;
    }
}

// gated[b,f,2t+s] = x[b,0,f,t,sel[b,s]]; one thread per (b,f,t), float2 store.
__global__ void gather_k(const float* __restrict__ x, const int* __restrict__ sel,
                         float* __restrict__ gated)
{
    const int idx = blockIdx.x * blockDim.x + threadIdx.x; // over B*80*400 = 2,048,000
    const int b = idx / 32000; // 80*400
    const int s0 = sel[b * 2], s1 = sel[b * 2 + 1];
    const float* xp = x + (size_t)idx * 5;
    float2 v;
    v.x = xp[s0];
    v.y = xp[s1];
    *(float2*)(gated + (size_t)idx * 2) = v;
}

static inline size_t alignup(size_t x) { return (x + 255) & ~(size_t)255; }

extern "C" void kernel_launch(void* const* d_in, const int* in_sizes, int n_in,
                              void* d_out, int out_size, void* d_ws, size_t ws_size,
                              hipStream_t stream)
{
    const float* x     = (const float*)d_in[0];
    const float* total = (const float*)d_in[1];
    const float* gw1 = (const float*)d_in[2];
    const float* g1  = (const float*)d_in[3];
    const float* b1  = (const float*)d_in[4];
    const float* gw2 = (const float*)d_in[5];
    const float* g2  = (const float*)d_in[6];
    const float* b2  = (const float*)d_in[7];
    const float* gw3 = (const float*)d_in[8];
    const float* g3  = (const float*)d_in[9];
    const float* b3  = (const float*)d_in[10];
    const float* gw4 = (const float*)d_in[11];
    const float* g4  = (const float*)d_in[12];
    const float* b4  = (const float*)d_in[13];
    const float* fw1 = (const float*)d_in[14];
    const float* fb1 = (const float*)d_in[15];
    const float* g1d = (const float*)d_in[16];
    const float* b1d = (const float*)d_in[17];
    const float* fw2 = (const float*)d_in[18];
    const float* fb2 = (const float*)d_in[19];
    const float* cw1 = (const float*)d_in[20];

    // workspace layout
    char* ws = (char*)d_ws;
    size_t off = 0;
    __hip_bfloat16* h1 = (__hip_bfloat16*)(ws + off); off = alignup(off + (size_t)40796160 * 2); // [64,32,40,498] bf16
    float* h2 = (float*)(ws + off); off = alignup(off + (size_t)9994240 * 4);  // [64,64,20,122]
    float* h3 = (float*)(ws + off); off = alignup(off + (size_t)2293760 * 4);  // [64,128,10,28]
    float* h4 = (float*)(ws + off); off = alignup(off + (size_t)409600 * 4);   // [64,256,5,5]
    int*   sel = (int*)(ws + off);  off = alignup(off + (size_t)64 * 2 * 4);   // [64,2]
    float* gated = (float*)(ws + off); off = alignup(off + (size_t)4096000 * 4); // [64,80,800]

    float* outc = (float*)d_out;            // [64,64,40,397]
    float* rw   = outc + (size_t)65044480;  // [64,5]

    // gate net
    conv_k<float, __hip_bfloat16, true, 5, 15><<<64 * 32, 256, 75 * 4, stream>>>(
        total, gw1, g1, b1, h1, 64, 1, 80, 2000, 32, 40, 498, 2, 4, 2, 2);
    conv_k<__hip_bfloat16, float, true, 5, 15><<<64 * 64, 256, 32 * 75 * 4, stream>>>(
        h1, gw2, g2, b2, h2, 64, 32, 40, 498, 64, 20, 122, 2, 4, 2, 2);
    conv_k<float, float, true, 5, 15><<<64 * 128, 256, 64 * 75 * 4, stream>>>(
        h2, gw3, g3, b3, h3, 64, 64, 20, 122, 128, 10, 28, 2, 4, 2, 2);
    conv_k<float, float, true, 5, 15><<<64 * 256, 256, 128 * 75 * 4, stream>>>(
        h3, gw4, g4, b4, h4, 64, 128, 10, 28, 256, 5, 5, 2, 4, 2, 2);

    // routing
    route_k<<<64, 256, 0, stream>>>(h4, fw1, fb1, g1d, b1d, fw2, fb2, rw, sel);

    // gather + stem conv
    gather_k<<<8000, 256, 0, stream>>>(x, sel, gated);
    conv_k<float, float, false, 7, 14><<<64 * 64, 256, 98 * 4, stream>>>(
        gated, cw1, nullptr, nullptr, outc, 64, 1, 80, 800, 64, 40, 397, 2, 2, 3, 3);
}

// Round 2
// 8272.387 us; speedup vs baseline: 3.5442x; 3.5442x over previous
//
#include <hip/hip_runtime.h>
#include <hip/hip_bf16.h>

#define DEV __device__ __forceinline__

DEV float loadf(const float* p) { return *p; }
DEV float loadf(const __hip_bfloat16* p) { return __bfloat162float(*p); }
DEV void storef(float* p, float v) { *p = v; }
DEV void storef(__hip_bfloat16* p, float v) { *p = __float2bfloat16(v); }

DEV float gelu_erf(float x) { return 0.5f * x * (1.0f + erff(x * 0.70710678118654752440f)); }

// weight transpose [OC][K] -> [K][OC] (reads coalesced along K)
__global__ void wtrans_k(const float* __restrict__ w, float* __restrict__ wt, int OC, int K) {
    int idx = blockIdx.x * blockDim.x + threadIdx.x;
    if (idx < OC * K) {
        int oc = idx / K, k = idx - oc * K;
        wt[(size_t)k * OC + oc] = w[idx];
    }
}

// Tiled direct conv. Block = (b, oh, ow-tile, oc-tile).
// LDS: input window [KH][SPAN] (fp32, zero-padded) + weight chunk [KH*KW][OCT]
// (from pre-transposed [K][OC]). Thread = (ocg, owg): micro-tile MOC oc x MOW ow,
// ow spread at stride 16 so B-reads are stride-SW (2-way bank alias = free).
template <typename InT, typename OutT, bool BNG, int KH, int KW, int SH, int SW,
          int MOC, int MOW, int NT>
__global__ __launch_bounds__(NT) void conv_tile(
    const InT* __restrict__ in, const float* __restrict__ wt,
    const float* __restrict__ gamma, const float* __restrict__ beta,
    OutT* __restrict__ out,
    int IC, int IH, int IW, int OC, int OH, int OW,
    int PH, int PW, int NOWT, int NOCB)
{
    constexpr int OWT = 16 * MOW;
    constexpr int SPAN = (OWT - 1) * SW + KW;
    constexpr int WOFF = (KH * SPAN + 3) & ~3;
    constexpr int NOCG = NT / 16;
    constexpr int OCT = NOCG * MOC;
    constexpr int KC = KH * KW;
    extern __shared__ float lds[];
    float* ilds = lds;
    float* wlds = lds + WOFF;

    int bid = blockIdx.x;
    const int owt = bid % NOWT; bid /= NOWT;
    const int oh  = bid % OH;   bid /= OH;
    const int ocb = bid % NOCB; bid /= NOCB;
    const int b   = bid;
    const int ow0 = owt * OWT;
    const int ocbase = ocb * OCT;
    const int tid = threadIdx.x;
    const int owg = tid & 15, ocg = tid >> 4;

    const int ih_base = oh * SH - PH;
    const int iw_base = ow0 * SW - PW;
    const InT* inb = in + (size_t)b * IC * IH * IW;
    const float* wbase = wt + ocbase;

    float acc[MOC][MOW];
#pragma unroll
    for (int m = 0; m < MOC; ++m)
#pragma unroll
        for (int j = 0; j < MOW; ++j) acc[m][j] = 0.f;

    for (int ic = 0; ic < IC; ++ic) {
        __syncthreads();
        // stage input window (zeros outside) - coalesced
        for (int idx = tid; idx < KH * SPAN; idx += NT) {
            int kh = idx / SPAN, s = idx - kh * SPAN;
            int ih = ih_base + kh, iw = iw_base + s;
            float v = 0.f;
            if ((unsigned)ih < (unsigned)IH && (unsigned)iw < (unsigned)IW)
                v = loadf(inb + ((size_t)ic * IH + ih) * IW + iw);
            ilds[idx] = v;
        }
        // stage weight chunk - coalesced read, conflict-free write
        const float* wsrc = wbase + (size_t)ic * KC * OC;
        for (int idx = tid; idx < KC * OCT; idx += NT) {
            int k = idx / OCT, oc = idx - k * OCT;
            wlds[idx] = wsrc[(size_t)k * OC + oc];
        }
        __syncthreads();
        for (int kh = 0; kh < KH; ++kh) {
            const float* brow = ilds + kh * SPAN + owg * SW;
            const float* wrow = wlds + kh * KW * OCT + ocg * MOC;
#pragma unroll
            for (int kw = 0; kw < KW; ++kw) {
                float a[MOC], bv[MOW];
#pragma unroll
                for (int m = 0; m < MOC; ++m) a[m] = wrow[kw * OCT + m];
#pragma unroll
                for (int j = 0; j < MOW; ++j) bv[j] = brow[kw + j * 16 * SW];
#pragma unroll
                for (int m = 0; m < MOC; ++m)
#pragma unroll
                    for (int j = 0; j < MOW; ++j)
                        acc[m][j] = fmaf(a[m], bv[j], acc[m][j]);
            }
        }
    }
#pragma unroll
    for (int m = 0; m < MOC; ++m) {
        const int oc = ocbase + ocg * MOC + m;
        float s = 1.f, bb = 0.f;
        if (BNG) { s = gamma[oc] * rsqrtf(1.0f + 1e-5f); bb = beta[oc]; }
        OutT* orow = out + (((size_t)b * OC + oc) * OH + oh) * OW;
#pragma unroll
        for (int j = 0; j < MOW; ++j) {
            int ow = ow0 + owg + 16 * j;
            if (ow < OW) {
                float y = fmaf(acc[m][j], s, bb);
                if (BNG) y = gelu_erf(y);
                storef(orow + ow, y);
            }
        }
    }
}

// conv4: [64,128,10,28] bf16 -> [64,256,5,5] f32. Whole input in LDS (71.7KB)
// + weight chunks [300][64] f32 (76.8KB). Grid = b*4 oc-tiles of 64.
__global__ __launch_bounds__(256) void conv4_k(
    const __hip_bfloat16* __restrict__ in, const float* __restrict__ wt,
    const float* __restrict__ gamma, const float* __restrict__ beta,
    float* __restrict__ out)
{
    extern __shared__ char raw[];
    ushort* ilds = (ushort*)raw;                 // 35840 bf16
    float* wlds = (float*)(raw + 35840 * 2);     // [300][64]
    const int b = blockIdx.x >> 2, ocb = blockIdx.x & 3;
    const int tid = threadIdx.x;
    const int p2 = tid & 31, ocg = tid >> 5;     // 8 ocg * 8 oc = 64
    const int p = p2 < 25 ? p2 : 24;
    const int oh = p / 5, ow = p - oh * 5;
    const int ih0 = oh * 2 - 2, iw0 = ow * 4 - 2;

    const ushort* src = (const ushort*)(in + (size_t)b * 35840);
    for (int idx = tid; idx < 35840; idx += 256) ilds[idx] = src[idx];

    float acc[8];
#pragma unroll
    for (int m = 0; m < 8; ++m) acc[m] = 0.f;

    for (int ch = 0; ch < 32; ++ch) {            // 4 ic per chunk, K-chunk = 300
        __syncthreads();
        const float* wsrc = wt + (size_t)(ch * 300) * 256 + ocb * 64;
        for (int idx = tid; idx < 300 * 64; idx += 256) {
            int k = idx >> 6, oc = idx & 63;
            wlds[idx] = wsrc[(size_t)k * 256 + oc];
        }
        __syncthreads();
#pragma unroll 1
        for (int icl = 0; icl < 4; ++icl) {
            const int ic = ch * 4 + icl;
            const ushort* ibase = ilds + ic * 280;
            const float* wrow = wlds + icl * 75 * 64 + ocg * 8;
#pragma unroll
            for (int kh = 0; kh < 5; ++kh) {
                const int ih = ih0 + kh;
                const bool rv = (unsigned)ih < 10u;
                const ushort* irow = ibase + (rv ? ih : 0) * 28;
#pragma unroll
                for (int kw = 0; kw < 15; ++kw) {
                    const int iw = iw0 + kw;
                    const bool cv = rv && ((unsigned)iw < 28u);
                    const int iwc = ((unsigned)iw < 28u) ? iw : 0;
                    float bvv = cv ? __bfloat162float(*(const __hip_bfloat16*)&irow[iwc]) : 0.f;
                    const float* wr = wrow + (kh * 15 + kw) * 64;
#pragma unroll
                    for (int m = 0; m < 8; ++m) acc[m] = fmaf(wr[m], bvv, acc[m]);
                }
            }
        }
    }
    if (p2 < 25) {
#pragma unroll
        for (int m = 0; m < 8; ++m) {
            int oc = ocb * 64 + ocg * 8 + m;
            float y = fmaf(acc[m], gamma[oc] * rsqrtf(1.0f + 1e-5f), beta[oc]);
            out[((size_t)b * 256 + oc) * 25 + p] = gelu_erf(y);
        }
    }
}

// Per-batch routing head.
__global__ void route_k(const float* __restrict__ h4,
                        const float* __restrict__ fw1, const float* __restrict__ fb1,
                        const float* __restrict__ g1d, const float* __restrict__ b1d,
                        const float* __restrict__ fw2, const float* __restrict__ fb2,
                        float* __restrict__ rw_out, int* __restrict__ sel_out)
{
    __shared__ float pooled[256];
    __shared__ float hmid[32];
    __shared__ float rwv[5];
    const int b = blockIdx.x, c = threadIdx.x;
    const float* p = h4 + ((size_t)b * 256 + c) * 25;
    float sum = 0.f;
#pragma unroll
    for (int i = 0; i < 25; ++i) sum += p[i];
    pooled[c] = sum * (1.0f / 25.0f);
    __syncthreads();
    if (c < 32) {
        float a = fb1[c];
        const float* wr = fw1 + c * 256;
        for (int i = 0; i < 256; ++i) a += pooled[i] * wr[i];
        a = gelu_erf(a);
        a = a * (g1d[c] * rsqrtf(1.0f + 1e-5f)) + b1d[c];
        hmid[c] = a;
    }
    __syncthreads();
    if (c < 5) {
        float a = fb2[c];
        const float* wr = fw2 + c * 32;
#pragma unroll
        for (int i = 0; i < 32; ++i) a += hmid[i] * wr[i];
        rwv[c] = a;
        rw_out[b * 5 + c] = a;
    }
    __syncthreads();
    if (c == 0) {
        int i1 = 0;
        for (int i = 1; i < 5; ++i) if (rwv[i] > rwv[i1]) i1 = i;
        int i2 = -1;
        for (int i = 0; i < 5; ++i) {
            if (i == i1) continue;
            if (i2 < 0 || rwv[i] > rwv[i2]) i2 = i;
        }
        sel_out[b * 2]     = i1 < i2 ? i1 : i2;
        sel_out[b * 2 + 1] = i1 < i2 ? i2 : i1;
    }
}

__global__ void gather_k(const float* __restrict__ x, const int* __restrict__ sel,
                         float* __restrict__ gated)
{
    const int idx = blockIdx.x * blockDim.x + threadIdx.x; // B*80*400
    const int b = idx / 32000;
    const int s0 = sel[b * 2], s1 = sel[b * 2 + 1];
    const float* xp = x + (size_t)idx * 5;
    float2 v;
    v.x = xp[s0];
    v.y = xp[s1];
    *(float2*)(gated + (size_t)idx * 2) = v;
}

extern "C" void kernel_launch(void* const* d_in, const int* in_sizes, int n_in,
                              void* d_out, int out_size, void* d_ws, size_t ws_size,
                              hipStream_t stream)
{
    const float* x     = (const float*)d_in[0];
    const float* total = (const float*)d_in[1];
    const float* gw1 = (const float*)d_in[2];
    const float* g1  = (const float*)d_in[3];
    const float* b1  = (const float*)d_in[4];
    const float* gw2 = (const float*)d_in[5];
    const float* g2  = (const float*)d_in[6];
    const float* b2  = (const float*)d_in[7];
    const float* gw3 = (const float*)d_in[8];
    const float* g3  = (const float*)d_in[9];
    const float* b3  = (const float*)d_in[10];
    const float* gw4 = (const float*)d_in[11];
    const float* g4  = (const float*)d_in[12];
    const float* b4  = (const float*)d_in[13];
    const float* fw1 = (const float*)d_in[14];
    const float* fb1 = (const float*)d_in[15];
    const float* g1d = (const float*)d_in[16];
    const float* b1d = (const float*)d_in[17];
    const float* fw2 = (const float*)d_in[18];
    const float* fb2 = (const float*)d_in[19];
    const float* cw1 = (const float*)d_in[20];

    char* ws = (char*)d_ws;
    size_t off = 0;
    auto alloc = [&](size_t bytes) { void* p = ws + off; off = (off + bytes + 255) & ~(size_t)255; return p; };
    __hip_bfloat16* h1 = (__hip_bfloat16*)alloc((size_t)40796160 * 2); // [64,32,40,498]
    __hip_bfloat16* h2 = (__hip_bfloat16*)alloc((size_t)9994240 * 2);  // [64,64,20,122]
    __hip_bfloat16* h3 = (__hip_bfloat16*)alloc((size_t)2293760 * 2);  // [64,128,10,28]
    float* h4    = (float*)alloc((size_t)409600 * 4);                  // [64,256,5,5]
    int*   sel   = (int*)alloc(512);
    float* gated = (float*)alloc((size_t)4096000 * 4);                 // [64,80,800]
    float* wt1 = (float*)alloc((size_t)2400 * 4);
    float* wt2 = (float*)alloc((size_t)153600 * 4);
    float* wt3 = (float*)alloc((size_t)614400 * 4);
    float* wt4 = (float*)alloc((size_t)2457600 * 4);
    float* wt5 = (float*)alloc((size_t)6272 * 4);

    float* outc = (float*)d_out;            // [64,64,40,397]
    float* rw   = outc + (size_t)65044480;  // [64,5]

    // weight transposes (tiny)
    wtrans_k<<<(32 * 75 + 255) / 256, 256, 0, stream>>>(gw1, wt1, 32, 75);
    wtrans_k<<<(64 * 2400 + 255) / 256, 256, 0, stream>>>(gw2, wt2, 64, 2400);
    wtrans_k<<<(128 * 4800 + 255) / 256, 256, 0, stream>>>(gw3, wt3, 128, 4800);
    wtrans_k<<<(256 * 9600 + 255) / 256, 256, 0, stream>>>(gw4, wt4, 256, 9600);
    wtrans_k<<<(64 * 98 + 255) / 256, 256, 0, stream>>>(cw1, wt5, 64, 98);

    // L1: IC=1 -> OC=32, MOC=4, OWT=64 (8 tiles). LDS=(1336+75*32)*4
    conv_tile<float, __hip_bfloat16, true, 5, 15, 2, 4, 4, 4, 128>
        <<<8 * 40 * 64, 128, (1336 + 2400) * 4, stream>>>(
        total, wt1, g1, b1, h1, 1, 80, 2000, 32, 40, 498, 2, 2, 8, 1);
    // L2: IC=32 -> OC=64, MOC=8, OWT=64 (2 tiles). LDS=(1336+4800)*4
    conv_tile<__hip_bfloat16, __hip_bfloat16, true, 5, 15, 2, 4, 8, 4, 128>
        <<<2 * 20 * 64, 128, (1336 + 4800) * 4, stream>>>(
        h1, wt2, g2, b2, h2, 32, 40, 498, 64, 20, 122, 2, 2, 2, 1);
    // L3: IC=64 -> OC=128 (2 oc-tiles of 64), OWT=32. LDS=(696+4800)*4
    conv_tile<__hip_bfloat16, __hip_bfloat16, true, 5, 15, 2, 4, 8, 2, 128>
        <<<1 * 10 * 2 * 64, 128, (696 + 4800) * 4, stream>>>(
        h2, wt3, g3, b3, h3, 64, 20, 122, 128, 10, 28, 2, 2, 1, 2);
    // L4 bespoke
    conv4_k<<<64 * 4, 256, 35840 * 2 + 300 * 64 * 4, stream>>>(h3, wt4, g4, b4, h4);

    route_k<<<64, 256, 0, stream>>>(h4, fw1, fb1, g1d, b1d, fw2, fb2, rw, sel);
    gather_k<<<8000, 256, 0, stream>>>(x, sel, gated);

    // L5 stem: IC=1 -> OC=64, K=7x14, stride 2,2, pad 3. OWT=64 (7 tiles). LDS=(980+6272)*4
    conv_tile<float, float, false, 7, 14, 2, 2, 8, 4, 128>
        <<<7 * 40 * 64, 128, (980 + 6272) * 4, stream>>>(
        gated, wt5, nullptr, nullptr, outc, 1, 80, 800, 64, 40, 397, 3, 3, 7, 1);
}

// Round 3
// 2577.673 us; speedup vs baseline: 11.3742x; 3.2092x over previous
//
#include <hip/hip_runtime.h>
#include <hip/hip_bf16.h>

#define DEV __device__ __forceinline__

typedef __attribute__((ext_vector_type(8))) short short8_t;
typedef __attribute__((ext_vector_type(4))) float f32x4;

DEV float loadf(const float* p) { return *p; }
DEV float loadf(const __hip_bfloat16* p) { return __bfloat162float(*p); }
DEV void storef(float* p, float v) { *p = v; }
DEV void storef(__hip_bfloat16* p, float v) { *p = __float2bfloat16(v); }

DEV float gelu_erf(float x) { return 0.5f * x * (1.0f + erff(x * 0.70710678118654752440f)); }

// weight transpose [OC][K] -> [K][OC]
__global__ void wtrans_k(const float* __restrict__ w, float* __restrict__ wt, int OC, int K) {
    int idx = blockIdx.x * blockDim.x + threadIdx.x;
    if (idx < OC * K) {
        int oc = idx / K, k = idx - oc * K;
        wt[(size_t)k * OC + oc] = w[idx];
    }
}

// f32 -> bf16 elementwise (for conv4 weights, [OC][K] stays K-contiguous)
__global__ void tobf16_k(const float* __restrict__ w, ushort* __restrict__ o, int n) {
    int idx = blockIdx.x * blockDim.x + threadIdx.x;
    if (idx < n) {
        __hip_bfloat16 v = __float2bfloat16(w[idx]);
        o[idx] = *(ushort*)&v;
    }
}

// im2col for conv4: A4[m][k], m = b*25 + (oh*5+ow)  (1600 rows), k = ic*75+kh*15+kw (9600)
__global__ void im2col4_k(const __hip_bfloat16* __restrict__ h3, ushort* __restrict__ A) {
    int idx = blockIdx.x * blockDim.x + threadIdx.x; // 1600*9600
    if (idx >= 1600 * 9600) return;
    int m = idx / 9600, k = idx - m * 9600;
    int b = m / 25, p = m - b * 25;
    int oh = p / 5, ow = p - oh * 5;
    int ic = k / 75, r = k - ic * 75;
    int kh = r / 15, kw = r - kh * 15;
    int ih = oh * 2 - 2 + kh, iw = ow * 4 - 2 + kw;
    ushort v = 0;
    if ((unsigned)ih < 10u && (unsigned)iw < 28u)
        v = ((const ushort*)h3)[(((size_t)b * 128 + ic) * 10 + ih) * 28 + iw];
    A[idx] = v;
}

// MFMA GEMM_BT: C[M=1600][N=256] = A[1600][9600] * B[256][9600]^T, bf16 in f32 out.
// Fused eval-BN + GELU on the N (=oc) axis. Tile 64x64, 4 waves (2x2), K-chunks of 32.
__global__ __launch_bounds__(256) void gemm4_k(
    const ushort* __restrict__ A, const ushort* __restrict__ B,
    const float* __restrict__ gamma, const float* __restrict__ beta,
    float* __restrict__ C)
{
    __shared__ ushort Al[64 * 32];
    __shared__ ushort Bl[64 * 32];
    const int nt = blockIdx.x & 3, mt = blockIdx.x >> 2;
    const int m0 = mt * 64, n0 = nt * 64;
    const int tid = threadIdx.x;
    const int w = tid >> 6, l = tid & 63;
    const int wr = (w >> 1) * 32, wc = (w & 1) * 32;
    const int lc = l & 15, lr = l >> 4;

    f32x4 acc[2][2];
#pragma unroll
    for (int i = 0; i < 2; ++i)
#pragma unroll
        for (int j = 0; j < 2; ++j) acc[i][j] = (f32x4){0.f, 0.f, 0.f, 0.f};

    const int arow = 16 * w + (l >> 2);       // staging row within tile for this lane
    const int acol8 = (l & 3) * 8;            // 8-elem column offset
    const ushort* ga = A + (size_t)(m0 + arow) * 9600 + acol8;
    const ushort* gb = B + (size_t)(n0 + arow) * 9600 + acol8;

    for (int kc = 0; kc < 300; ++kc) {
        __syncthreads();
        __builtin_amdgcn_global_load_lds(ga + kc * 32, &Al[16 * w * 32], 16, 0, 0);
        __builtin_amdgcn_global_load_lds(gb + kc * 32, &Bl[16 * w * 32], 16, 0, 0);
        __syncthreads();
        short8_t a0 = *(const short8_t*)&Al[(wr + lc) * 32 + 8 * lr];
        short8_t a1 = *(const short8_t*)&Al[(wr + 16 + lc) * 32 + 8 * lr];
        short8_t b0 = *(const short8_t*)&Bl[(wc + lc) * 32 + 8 * lr];
        short8_t b1 = *(const short8_t*)&Bl[(wc + 16 + lc) * 32 + 8 * lr];
        acc[0][0] = __builtin_amdgcn_mfma_f32_16x16x32_bf16(a0, b0, acc[0][0], 0, 0, 0);
        acc[0][1] = __builtin_amdgcn_mfma_f32_16x16x32_bf16(a0, b1, acc[0][1], 0, 0, 0);
        acc[1][0] = __builtin_amdgcn_mfma_f32_16x16x32_bf16(a1, b0, acc[1][0], 0, 0, 0);
        acc[1][1] = __builtin_amdgcn_mfma_f32_16x16x32_bf16(a1, b1, acc[1][1], 0, 0, 0);
    }

#pragma unroll
    for (int mi = 0; mi < 2; ++mi)
#pragma unroll
        for (int nj = 0; nj < 2; ++nj) {
            const int n = n0 + wc + 16 * nj + lc;
            const float s = gamma[n] * rsqrtf(1.0f + 1e-5f);
            const float bb = beta[n];
#pragma unroll
            for (int r = 0; r < 4; ++r) {
                const int m = m0 + wr + 16 * mi + 4 * lr + r;
                C[(size_t)m * 256 + n] = gelu_erf(fmaf(acc[mi][nj][r], s, bb));
            }
        }
}

// Tiled direct conv (VALU). Block = (b, oh, ow-tile, oc-tile).
template <typename InT, typename OutT, bool BNG, int KH, int KW, int SH, int SW,
          int MOC, int MOW, int NT>
__global__ __launch_bounds__(NT) void conv_tile(
    const InT* __restrict__ in, const float* __restrict__ wt,
    const float* __restrict__ gamma, const float* __restrict__ beta,
    OutT* __restrict__ out,
    int IC, int IH, int IW, int OC, int OH, int OW,
    int PH, int PW, int NOWT, int NOCB)
{
    constexpr int OWT = 16 * MOW;
    constexpr int SPAN = (OWT - 1) * SW + KW;
    constexpr int WOFF = (KH * SPAN + 3) & ~3;
    constexpr int NOCG = NT / 16;
    constexpr int OCT = NOCG * MOC;
    constexpr int KC = KH * KW;
    extern __shared__ float lds[];
    float* ilds = lds;
    float* wlds = lds + WOFF;

    int bid = blockIdx.x;
    const int owt = bid % NOWT; bid /= NOWT;
    const int oh  = bid % OH;   bid /= OH;
    const int ocb = bid % NOCB; bid /= NOCB;
    const int b   = bid;
    const int ow0 = owt * OWT;
    const int ocbase = ocb * OCT;
    const int tid = threadIdx.x;
    const int owg = tid & 15, ocg = tid >> 4;

    const int ih_base = oh * SH - PH;
    const int iw_base = ow0 * SW - PW;
    const InT* inb = in + (size_t)b * IC * IH * IW;
    const float* wbase = wt + ocbase;

    float acc[MOC][MOW];
#pragma unroll
    for (int m = 0; m < MOC; ++m)
#pragma unroll
        for (int j = 0; j < MOW; ++j) acc[m][j] = 0.f;

    for (int ic = 0; ic < IC; ++ic) {
        __syncthreads();
        for (int idx = tid; idx < KH * SPAN; idx += NT) {
            int kh = idx / SPAN, s = idx - kh * SPAN;
            int ih = ih_base + kh, iw = iw_base + s;
            float v = 0.f;
            if ((unsigned)ih < (unsigned)IH && (unsigned)iw < (unsigned)IW)
                v = loadf(inb + ((size_t)ic * IH + ih) * IW + iw);
            ilds[idx] = v;
        }
        const float* wsrc = wbase + (size_t)ic * KC * OC;
        for (int idx = tid; idx < KC * OCT; idx += NT) {
            int k = idx / OCT, oc = idx - k * OCT;
            wlds[idx] = wsrc[(size_t)k * OC + oc];
        }
        __syncthreads();
        for (int kh = 0; kh < KH; ++kh) {
            const float* brow = ilds + kh * SPAN + owg * SW;
            const float* wrow = wlds + kh * KW * OCT + ocg * MOC;
#pragma unroll
            for (int kw = 0; kw < KW; ++kw) {
                float a[MOC], bv[MOW];
#pragma unroll
                for (int m = 0; m < MOC; ++m) a[m] = wrow[kw * OCT + m];
#pragma unroll
                for (int j = 0; j < MOW; ++j) bv[j] = brow[kw + j * 16 * SW];
#pragma unroll
                for (int m = 0; m < MOC; ++m)
#pragma unroll
                    for (int j = 0; j < MOW; ++j)
                        acc[m][j] = fmaf(a[m], bv[j], acc[m][j]);
            }
        }
    }
#pragma unroll
    for (int m = 0; m < MOC; ++m) {
        const int oc = ocbase + ocg * MOC + m;
        float s = 1.f, bb = 0.f;
        if (BNG) { s = gamma[oc] * rsqrtf(1.0f + 1e-5f); bb = beta[oc]; }
        OutT* orow = out + (((size_t)b * OC + oc) * OH + oh) * OW;
#pragma unroll
        for (int j = 0; j < MOW; ++j) {
            int ow = ow0 + owg + 16 * j;
            if (ow < OW) {
                float y = fmaf(acc[m][j], s, bb);
                if (BNG) y = gelu_erf(y);
                storef(orow + ow, y);
            }
        }
    }
}

// Routing head; h4t is GEMM-layout [1600][256] = [(b,p)][oc].
__global__ void route_k(const float* __restrict__ h4t,
                        const float* __restrict__ fw1, const float* __restrict__ fb1,
                        const float* __restrict__ g1d, const float* __restrict__ b1d,
                        const float* __restrict__ fw2, const float* __restrict__ fb2,
                        float* __restrict__ rw_out, int* __restrict__ sel_out)
{
    __shared__ float pooled[256];
    __shared__ float hmid[32];
    __shared__ float rwv[5];
    const int b = blockIdx.x, c = threadIdx.x;
    const float* p = h4t + (size_t)b * 25 * 256 + c;
    float sum = 0.f;
#pragma unroll
    for (int i = 0; i < 25; ++i) sum += p[i * 256];
    pooled[c] = sum * (1.0f / 25.0f);
    __syncthreads();
    if (c < 32) {
        float a = fb1[c];
        const float* wr = fw1 + c * 256;
        for (int i = 0; i < 256; ++i) a += pooled[i] * wr[i];
        a = gelu_erf(a);
        a = a * (g1d[c] * rsqrtf(1.0f + 1e-5f)) + b1d[c];
        hmid[c] = a;
    }
    __syncthreads();
    if (c < 5) {
        float a = fb2[c];
        const float* wr = fw2 + c * 32;
#pragma unroll
        for (int i = 0; i < 32; ++i) a += hmid[i] * wr[i];
        rwv[c] = a;
        rw_out[b * 5 + c] = a;
    }
    __syncthreads();
    if (c == 0) {
        int i1 = 0;
        for (int i = 1; i < 5; ++i) if (rwv[i] > rwv[i1]) i1 = i;
        int i2 = -1;
        for (int i = 0; i < 5; ++i) {
            if (i == i1) continue;
            if (i2 < 0 || rwv[i] > rwv[i2]) i2 = i;
        }
        sel_out[b * 2]     = i1 < i2 ? i1 : i2;
        sel_out[b * 2 + 1] = i1 < i2 ? i2 : i1;
    }
}

__global__ void gather_k(const float* __restrict__ x, const int* __restrict__ sel,
                         float* __restrict__ gated)
{
    const int idx = blockIdx.x * blockDim.x + threadIdx.x; // B*80*400
    const int b = idx / 32000;
    const int s0 = sel[b * 2], s1 = sel[b * 2 + 1];
    const float* xp = x + (size_t)idx * 5;
    float2 v;
    v.x = xp[s0];
    v.y = xp[s1];
    *(float2*)(gated + (size_t)idx * 2) = v;
}

extern "C" void kernel_launch(void* const* d_in, const int* in_sizes, int n_in,
                              void* d_out, int out_size, void* d_ws, size_t ws_size,
                              hipStream_t stream)
{
    const float* x     = (const float*)d_in[0];
    const float* total = (const float*)d_in[1];
    const float* gw1 = (const float*)d_in[2];
    const float* g1  = (const float*)d_in[3];
    const float* b1  = (const float*)d_in[4];
    const float* gw2 = (const float*)d_in[5];
    const float* g2  = (const float*)d_in[6];
    const float* b2  = (const float*)d_in[7];
    const float* gw3 = (const float*)d_in[8];
    const float* g3  = (const float*)d_in[9];
    const float* b3  = (const float*)d_in[10];
    const float* gw4 = (const float*)d_in[11];
    const float* g4  = (const float*)d_in[12];
    const float* b4  = (const float*)d_in[13];
    const float* fw1 = (const float*)d_in[14];
    const float* fb1 = (const float*)d_in[15];
    const float* g1d = (const float*)d_in[16];
    const float* b1d = (const float*)d_in[17];
    const float* fw2 = (const float*)d_in[18];
    const float* fb2 = (const float*)d_in[19];
    const float* cw1 = (const float*)d_in[20];

    char* ws = (char*)d_ws;
    size_t off = 0;
    auto alloc = [&](size_t bytes) { void* p = ws + off; off = (off + bytes + 255) & ~(size_t)255; return p; };
    __hip_bfloat16* h1 = (__hip_bfloat16*)alloc((size_t)40796160 * 2); // [64,32,40,498]
    __hip_bfloat16* h2 = (__hip_bfloat16*)alloc((size_t)9994240 * 2);  // [64,64,20,122]
    __hip_bfloat16* h3 = (__hip_bfloat16*)alloc((size_t)2293760 * 2);  // [64,128,10,28]
    float* h4t   = (float*)alloc((size_t)409600 * 4);                  // [1600][256] GEMM layout
    int*   sel   = (int*)alloc(512);
    float* gated = (float*)alloc((size_t)4096000 * 4);                 // [64,80,800]
    float* wt1 = (float*)alloc((size_t)2400 * 4);
    float* wt2 = (float*)alloc((size_t)153600 * 4);
    float* wt3 = (float*)alloc((size_t)614400 * 4);
    float* wt5 = (float*)alloc((size_t)6272 * 4);
    // aliases into dead regions (safe by launch order):
    ushort* A4  = (ushort*)h1;   // 1600*9600*2 = 30.7MB <= h1's 81.6MB; h1 dead after conv2
    ushort* w4b = (ushort*)h2;   // 9600*256*2 = 4.9MB  <= h2's 20MB;  h2 dead after conv3

    float* outc = (float*)d_out;            // [64,64,40,397]
    float* rw   = outc + (size_t)65044480;  // [64,5]

    // weight transposes (tiny)
    wtrans_k<<<(32 * 75 + 255) / 256, 256, 0, stream>>>(gw1, wt1, 32, 75);
    wtrans_k<<<(64 * 2400 + 255) / 256, 256, 0, stream>>>(gw2, wt2, 64, 2400);
    wtrans_k<<<(128 * 4800 + 255) / 256, 256, 0, stream>>>(gw3, wt3, 128, 4800);
    wtrans_k<<<(64 * 98 + 255) / 256, 256, 0, stream>>>(cw1, wt5, 64, 98);

    // L1: IC=1 -> OC=32
    conv_tile<float, __hip_bfloat16, true, 5, 15, 2, 4, 4, 4, 128>
        <<<8 * 40 * 64, 128, (1336 + 2400) * 4, stream>>>(
        total, wt1, g1, b1, h1, 1, 80, 2000, 32, 40, 498, 2, 2, 8, 1);
    // L2: IC=32 -> OC=64
    conv_tile<__hip_bfloat16, __hip_bfloat16, true, 5, 15, 2, 4, 8, 4, 128>
        <<<2 * 20 * 64, 128, (1336 + 4800) * 4, stream>>>(
        h1, wt2, g2, b2, h2, 32, 40, 498, 64, 20, 122, 2, 2, 2, 1);
    // L3: IC=64 -> OC=128
    conv_tile<__hip_bfloat16, __hip_bfloat16, true, 5, 15, 2, 4, 8, 2, 128>
        <<<1 * 10 * 2 * 64, 128, (696 + 4800) * 4, stream>>>(
        h2, wt3, g3, b3, h3, 64, 20, 122, 128, 10, 28, 2, 2, 1, 2);

    // L4 as explicit im2col + MFMA GEMM (h1, h2 are dead now; aliases safe)
    tobf16_k<<<(2457600 + 255) / 256, 256, 0, stream>>>(gw4, w4b, 2457600);
    im2col4_k<<<(15360000 + 255) / 256, 256, 0, stream>>>(h3, A4);
    gemm4_k<<<100, 256, 0, stream>>>(A4, w4b, g4, b4, h4t);

    route_k<<<64, 256, 0, stream>>>(h4t, fw1, fb1, g1d, b1d, fw2, fb2, rw, sel);
    gather_k<<<8000, 256, 0, stream>>>(x, sel, gated);

    // L5 stem
    conv_tile<float, float, false, 7, 14, 2, 2, 8, 4, 128>
        <<<7 * 40 * 64, 128, (980 + 6272) * 4, stream>>>(
        gated, wt5, nullptr, nullptr, outc, 1, 80, 800, 64, 40, 397, 3, 3, 7, 1);
}

// Round 4
// 853.848 us; speedup vs baseline: 34.3376x; 3.0189x over previous
//
#include <hip/hip_runtime.h>
#include <hip/hip_bf16.h>

#define DEV __device__ __forceinline__

typedef __attribute__((ext_vector_type(8))) short short8_t;
typedef __attribute__((ext_vector_type(4))) float f32x4;

DEV float loadf(const float* p) { return *p; }
DEV float loadf(const __hip_bfloat16* p) { return __bfloat162float(*p); }

DEV float gelu_erf(float x) { return 0.5f * x * (1.0f + erff(x * 0.70710678118654752440f)); }

// ---------- weight prep ----------
// [OC][K] -> [K][OC] f32 (conv1, conv5 VALU path)
__global__ void wtrans_k(const float* __restrict__ w, float* __restrict__ wt, int OC, int K) {
    int idx = blockIdx.x * blockDim.x + threadIdx.x;
    if (idx < OC * K) {
        int oc = idx / K, k = idx - oc * K;
        wt[(size_t)k * OC + oc] = w[idx];
    }
}

// gwX [OC][IC][KH][KW] f32 -> wp [KH*KW][OC][IC] bf16
__global__ void wperm_k(const float* __restrict__ w, ushort* __restrict__ wp,
                        int OC, int IC, int KC) {
    int idx = blockIdx.x * blockDim.x + threadIdx.x; // over KC*OC*IC, ic fastest
    if (idx >= KC * OC * IC) return;
    int ic = idx % IC, t = idx / IC;
    int oc = t % OC, kc = t / OC;
    __hip_bfloat16 v = __float2bfloat16(w[((size_t)oc * IC + ic) * KC + kc]);
    wp[idx] = *(ushort*)&v;
}

// gw4 [256][128][5][15] f32 -> w4p [256][ (kh*15+kw)*128+ic ] bf16
__global__ void wperm4_k(const float* __restrict__ w, ushort* __restrict__ wp) {
    int idx = blockIdx.x * blockDim.x + threadIdx.x; // 256*9600
    if (idx >= 256 * 9600) return;
    int kp = idx % 9600, oc = idx / 9600;
    int ic = kp & 127, kc = kp >> 7;
    __hip_bfloat16 v = __float2bfloat16(w[((size_t)oc * 128 + ic) * 75 + kc]);
    wp[idx] = *(ushort*)&v;
}

// ---------- conv1 / conv5: VALU tiled direct conv ----------
template <typename InT, typename OutT, bool BNG, bool NHWC, int KH, int KW, int SH, int SW,
          int MOC, int MOW, int NT>
__global__ __launch_bounds__(NT) void conv_tile(
    const InT* __restrict__ in, const float* __restrict__ wt,
    const float* __restrict__ gamma, const float* __restrict__ beta,
    OutT* __restrict__ out,
    int IC, int IH, int IW, int OC, int OH, int OW,
    int PH, int PW, int NOWT, int NOCB)
{
    constexpr int OWT = 16 * MOW;
    constexpr int SPAN = (OWT - 1) * SW + KW;
    constexpr int WOFF = (KH * SPAN + 3) & ~3;
    constexpr int NOCG = NT / 16;
    constexpr int OCT = NOCG * MOC;
    constexpr int KC = KH * KW;
    extern __shared__ float lds[];
    float* ilds = lds;
    float* wlds = lds + WOFF;

    int bid = blockIdx.x;
    const int owt = bid % NOWT; bid /= NOWT;
    const int oh  = bid % OH;   bid /= OH;
    const int ocb = bid % NOCB; bid /= NOCB;
    const int b   = bid;
    const int ow0 = owt * OWT;
    const int ocbase = ocb * OCT;
    const int tid = threadIdx.x;
    const int owg = tid & 15, ocg = tid >> 4;

    const int ih_base = oh * SH - PH;
    const int iw_base = ow0 * SW - PW;
    const InT* inb = in + (size_t)b * IC * IH * IW;
    const float* wbase = wt + ocbase;

    float acc[MOC][MOW];
#pragma unroll
    for (int m = 0; m < MOC; ++m)
#pragma unroll
        for (int j = 0; j < MOW; ++j) acc[m][j] = 0.f;

    for (int ic = 0; ic < IC; ++ic) {
        __syncthreads();
        for (int idx = tid; idx < KH * SPAN; idx += NT) {
            int kh = idx / SPAN, s = idx - kh * SPAN;
            int ih = ih_base + kh, iw = iw_base + s;
            float v = 0.f;
            if ((unsigned)ih < (unsigned)IH && (unsigned)iw < (unsigned)IW)
                v = loadf(inb + ((size_t)ic * IH + ih) * IW + iw);
            ilds[idx] = v;
        }
        const float* wsrc = wbase + (size_t)ic * KC * OC;
        for (int idx = tid; idx < KC * OCT; idx += NT) {
            int k = idx / OCT, oc = idx - k * OCT;
            wlds[idx] = wsrc[(size_t)k * OC + oc];
        }
        __syncthreads();
        for (int kh = 0; kh < KH; ++kh) {
            const float* brow = ilds + kh * SPAN + owg * SW;
            const float* wrow = wlds + kh * KW * OCT + ocg * MOC;
#pragma unroll
            for (int kw = 0; kw < KW; ++kw) {
                float a[MOC], bv[MOW];
#pragma unroll
                for (int m = 0; m < MOC; ++m) a[m] = wrow[kw * OCT + m];
#pragma unroll
                for (int j = 0; j < MOW; ++j) bv[j] = brow[kw + j * 16 * SW];
#pragma unroll
                for (int m = 0; m < MOC; ++m)
#pragma unroll
                    for (int j = 0; j < MOW; ++j)
                        acc[m][j] = fmaf(a[m], bv[j], acc[m][j]);
            }
        }
    }
    if (NHWC) {
        // pack MOC contiguous oc -> one 2*MOC-byte store per ow
        ushort* outn = (ushort*)out + ((size_t)b * OH + oh) * OW * OC;
        const int ocb0 = ocbase + ocg * MOC;
        float s[MOC], bb[MOC];
#pragma unroll
        for (int m = 0; m < MOC; ++m) {
            s[m] = BNG ? gamma[ocb0 + m] * rsqrtf(1.0f + 1e-5f) : 1.f;
            bb[m] = BNG ? beta[ocb0 + m] : 0.f;
        }
#pragma unroll
        for (int j = 0; j < MOW; ++j) {
            int ow = ow0 + owg + 16 * j;
            if (ow < OW) {
                ushort pk[MOC];
#pragma unroll
                for (int m = 0; m < MOC; ++m) {
                    float y = fmaf(acc[m][j], s[m], bb[m]);
                    if (BNG) y = gelu_erf(y);
                    __hip_bfloat16 h = __float2bfloat16(y);
                    pk[m] = *(ushort*)&h;
                }
                if (MOC == 4) *(ushort4*)(outn + (size_t)ow * OC + ocb0) = *(ushort4*)pk;
                else {
#pragma unroll
                    for (int m = 0; m < MOC; ++m) outn[(size_t)ow * OC + ocb0 + m] = pk[m];
                }
            }
        }
    } else {
#pragma unroll
        for (int m = 0; m < MOC; ++m) {
            const int oc = ocbase + ocg * MOC + m;
            float s = 1.f, bb = 0.f;
            if (BNG) { s = gamma[oc] * rsqrtf(1.0f + 1e-5f); bb = beta[oc]; }
            float* orow = (float*)out + (((size_t)b * OC + oc) * OH + oh) * OW;
#pragma unroll
            for (int j = 0; j < MOW; ++j) {
                int ow = ow0 + owg + 16 * j;
                if (ow < OW) {
                    float y = fmaf(acc[m][j], s, bb);
                    if (BNG) y = gelu_erf(y);
                    orow[ow] = y;
                }
            }
        }
    }
}

// ---------- implicit-GEMM MFMA conv (NHWC bf16 -> NHWC bf16), stride (2,4), K (5,15), pad 2 ----------
// Block tile: M_BLK ow-positions x OC. Waves: NWM x NWN, wave-tile 32x32.
// LDS: per-kh input row, [pos][IC] with XOR-swizzled 16B slots. Weights [75][OC][IC] bf16 from global.
template <int M_BLK, int OC, int ICT, int NICC, int NWM, int NWN>
__global__ __launch_bounds__(64 * NWM * NWN) void convmm_k(
    const ushort* __restrict__ in, const ushort* __restrict__ wp,
    const float* __restrict__ gamma, const float* __restrict__ beta,
    ushort* __restrict__ out,
    int IH, int IW, int OH, int OW, int NOWT)
{
    constexpr int KH = 5, KW = 15, SH = 2, SW = 4, PH = 2, PW = 2;
    constexpr int SPAN = (M_BLK - 1) * SW + KW;
    constexpr int ICB = ICT * 2;            // bytes per position
    constexpr int NSL = ICT / 8;            // 16B slots per position
    constexpr int KEYM = NSL - 1;
    constexpr int NT = 64 * NWM * NWN;
    constexpr int NUNITS = SPAN * NSL;

    __shared__ __align__(16) ushort Abuf[2][SPAN * ICT];

    int bid = blockIdx.x;
    const int owt = bid % NOWT; bid /= NOWT;
    const int oh  = bid % OH;
    const int b   = bid / OH;
    const int ow0 = owt * M_BLK;
    const int tid = threadIdx.x;
    const int w = tid >> 6, l = tid & 63;
    const int wn = w % NWN, wm = w / NWN;
    const int m_wave = wm * 32, n_wave = wn * 32;
    const int lc = l & 15, lr = l >> 4;

    const int ih0 = oh * SH - PH;
    const int iw0 = ow0 * SW - PW;
    const ushort* inb = in + (size_t)b * IH * IW * ICT;

    f32x4 acc[2][2];
#pragma unroll
    for (int i = 0; i < 2; ++i)
#pragma unroll
        for (int j = 0; j < 2; ++j) acc[i][j] = (f32x4){0.f, 0.f, 0.f, 0.f};

    auto stage = [&](int kh, int buf) {
        const int ih = ih0 + kh;
        char* dst = (char*)Abuf[buf];
        if ((unsigned)ih < (unsigned)IH) {
            const ushort* src = inb + (size_t)ih * IW * ICT;
            for (int u = tid; u < NUNITS; u += NT) {
                int p = u / NSL, sl = u - p * NSL;
                int iw = iw0 + p;
                uint4 v = {0u, 0u, 0u, 0u};
                if ((unsigned)iw < (unsigned)IW)
                    v = *(const uint4*)(src + (size_t)iw * ICT + sl * 8);
                *(uint4*)(dst + p * ICB + ((sl ^ ((p >> 2) & KEYM)) << 4)) = v;
            }
        } else {
            for (int u = tid; u < NUNITS; u += NT) {
                int p = u / NSL, sl = u - p * NSL;
                *(uint4*)(dst + p * ICB + ((sl ^ ((p >> 2) & KEYM)) << 4)) = (uint4){0u, 0u, 0u, 0u};
            }
        }
    };

    stage(0, 0);
#pragma unroll 1
    for (int kh = 0; kh < KH; ++kh) {
        __syncthreads();
        if (kh + 1 < KH) stage(kh + 1, (kh + 1) & 1);   // overlap with compute below
        const char* buf = (const char*)Abuf[kh & 1];
#pragma unroll 1
        for (int kw = 0; kw < KW; ++kw) {
#pragma unroll
            for (int icc = 0; icc < NICC; ++icc) {
                short8_t a[2], bf[2];
#pragma unroll
                for (int mi = 0; mi < 2; ++mi) {
                    const int r = m_wave + mi * 16 + lc;
                    const int p = SW * r + kw;
                    const int sl = icc * 4 + lr;
                    a[mi] = *(const short8_t*)(buf + p * ICB + ((sl ^ ((p >> 2) & KEYM)) << 4));
                }
                const ushort* wb = wp + ((size_t)(kh * KW + kw) * OC + n_wave + lc) * ICT + icc * 32 + lr * 8;
#pragma unroll
                for (int nj = 0; nj < 2; ++nj)
                    bf[nj] = *(const short8_t*)(wb + nj * 16 * ICT);
#pragma unroll
                for (int mi = 0; mi < 2; ++mi)
#pragma unroll
                    for (int nj = 0; nj < 2; ++nj)
                        acc[mi][nj] = __builtin_amdgcn_mfma_f32_16x16x32_bf16(a[mi], bf[nj], acc[mi][nj], 0, 0, 0);
            }
        }
    }

    // epilogue: BN + GELU, NHWC bf16
    ushort* outb = out + ((size_t)b * OH + oh) * OW * OC;
#pragma unroll
    for (int nj = 0; nj < 2; ++nj) {
        const int n = n_wave + nj * 16 + lc;
        const float s = gamma[n] * rsqrtf(1.0f + 1e-5f);
        const float bb = beta[n];
#pragma unroll
        for (int mi = 0; mi < 2; ++mi) {
#pragma unroll
            for (int r = 0; r < 4; ++r) {
                const int m = m_wave + mi * 16 + lr * 4 + r;
                const int ow = ow0 + m;
                if (ow < OW) {
                    float y = gelu_erf(fmaf(acc[mi][nj][r], s, bb));
                    __hip_bfloat16 h = __float2bfloat16(y);
                    outb[(size_t)ow * OC + n] = *(ushort*)&h;
                }
            }
        }
    }
}

// ---------- conv4: im2col (NHWC, k' = (kh*15+kw)*128+ic) + MFMA GEMM ----------
__global__ void im2col4_k(const ushort* __restrict__ h3, ushort* __restrict__ A) {
    int idx = blockIdx.x * blockDim.x + threadIdx.x; // 1600*9600
    if (idx >= 1600 * 9600) return;
    int kp = idx % 9600, m = idx / 9600;
    int ic = kp & 127, kc = kp >> 7;
    int b = m / 25, p = m - b * 25;
    int oh = p / 5, ow = p - oh * 5;
    int kh = kc / 15, kw = kc - kh * 15;
    int ih = oh * 2 - 2 + kh, iw = ow * 4 - 2 + kw;
    ushort v = 0;
    if ((unsigned)ih < 10u && (unsigned)iw < 28u)
        v = h3[(((size_t)b * 10 + ih) * 28 + iw) * 128 + ic];
    A[idx] = v;
}

__global__ __launch_bounds__(256) void gemm4_k(
    const ushort* __restrict__ A, const ushort* __restrict__ B,
    const float* __restrict__ gamma, const float* __restrict__ beta,
    float* __restrict__ C)
{
    __shared__ ushort Al[64 * 32];
    __shared__ ushort Bl[64 * 32];
    const int nt = blockIdx.x & 3, mt = blockIdx.x >> 2;
    const int m0 = mt * 64, n0 = nt * 64;
    const int tid = threadIdx.x;
    const int w = tid >> 6, l = tid & 63;
    const int wr = (w >> 1) * 32, wc = (w & 1) * 32;
    const int lc = l & 15, lr = l >> 4;

    f32x4 acc[2][2];
#pragma unroll
    for (int i = 0; i < 2; ++i)
#pragma unroll
        for (int j = 0; j < 2; ++j) acc[i][j] = (f32x4){0.f, 0.f, 0.f, 0.f};

    const int arow = 16 * w + (l >> 2);
    const int acol8 = (l & 3) * 8;
    const ushort* ga = A + (size_t)(m0 + arow) * 9600 + acol8;
    const ushort* gb = B + (size_t)(n0 + arow) * 9600 + acol8;

    for (int kc = 0; kc < 300; ++kc) {
        __syncthreads();
        __builtin_amdgcn_global_load_lds(ga + kc * 32, &Al[16 * w * 32], 16, 0, 0);
        __builtin_amdgcn_global_load_lds(gb + kc * 32, &Bl[16 * w * 32], 16, 0, 0);
        __syncthreads();
        short8_t a0 = *(const short8_t*)&Al[(wr + lc) * 32 + 8 * lr];
        short8_t a1 = *(const short8_t*)&Al[(wr + 16 + lc) * 32 + 8 * lr];
        short8_t b0 = *(const short8_t*)&Bl[(wc + lc) * 32 + 8 * lr];
        short8_t b1 = *(const short8_t*)&Bl[(wc + 16 + lc) * 32 + 8 * lr];
        acc[0][0] = __builtin_amdgcn_mfma_f32_16x16x32_bf16(a0, b0, acc[0][0], 0, 0, 0);
        acc[0][1] = __builtin_amdgcn_mfma_f32_16x16x32_bf16(a0, b1, acc[0][1], 0, 0, 0);
        acc[1][0] = __builtin_amdgcn_mfma_f32_16x16x32_bf16(a1, b0, acc[1][0], 0, 0, 0);
        acc[1][1] = __builtin_amdgcn_mfma_f32_16x16x32_bf16(a1, b1, acc[1][1], 0, 0, 0);
    }

#pragma unroll
    for (int mi = 0; mi < 2; ++mi)
#pragma unroll
        for (int nj = 0; nj < 2; ++nj) {
            const int n = n0 + wc + 16 * nj + lc;
            const float s = gamma[n] * rsqrtf(1.0f + 1e-5f);
            const float bb = beta[n];
#pragma unroll
            for (int r = 0; r < 4; ++r) {
                const int m = m0 + wr + 16 * mi + 4 * lr + r;
                C[(size_t)m * 256 + n] = gelu_erf(fmaf(acc[mi][nj][r], s, bb));
            }
        }
}

// ---------- routing head ----------
__global__ void route_k(const float* __restrict__ h4t,
                        const float* __restrict__ fw1, const float* __restrict__ fb1,
                        const float* __restrict__ g1d, const float* __restrict__ b1d,
                        const float* __restrict__ fw2, const float* __restrict__ fb2,
                        float* __restrict__ rw_out, int* __restrict__ sel_out)
{
    __shared__ float pooled[256];
    __shared__ float hmid[32];
    __shared__ float rwv[5];
    const int b = blockIdx.x, c = threadIdx.x;
    const float* p = h4t + (size_t)b * 25 * 256 + c;
    float sum = 0.f;
#pragma unroll
    for (int i = 0; i < 25; ++i) sum += p[i * 256];
    pooled[c] = sum * (1.0f / 25.0f);
    __syncthreads();
    if (c < 32) {
        float a = fb1[c];
        const float* wr = fw1 + c * 256;
        for (int i = 0; i < 256; ++i) a += pooled[i] * wr[i];
        a = gelu_erf(a);
        a = a * (g1d[c] * rsqrtf(1.0f + 1e-5f)) + b1d[c];
        hmid[c] = a;
    }
    __syncthreads();
    if (c < 5) {
        float a = fb2[c];
        const float* wr = fw2 + c * 32;
#pragma unroll
        for (int i = 0; i < 32; ++i) a += hmid[i] * wr[i];
        rwv[c] = a;
        rw_out[b * 5 + c] = a;
    }
    __syncthreads();
    if (c == 0) {
        int i1 = 0;
        for (int i = 1; i < 5; ++i) if (rwv[i] > rwv[i1]) i1 = i;
        int i2 = -1;
        for (int i = 0; i < 5; ++i) {
            if (i == i1) continue;
            if (i2 < 0 || rwv[i] > rwv[i2]) i2 = i;
        }
        sel_out[b * 2]     = i1 < i2 ? i1 : i2;
        sel_out[b * 2 + 1] = i1 < i2 ? i2 : i1;
    }
}

__global__ void gather_k(const float* __restrict__ x, const int* __restrict__ sel,
                         float* __restrict__ gated)
{
    const int idx = blockIdx.x * blockDim.x + threadIdx.x; // B*80*400
    const int b = idx / 32000;
    const int s0 = sel[b * 2], s1 = sel[b * 2 + 1];
    const float* xp = x + (size_t)idx * 5;
    float2 v;
    v.x = xp[s0];
    v.y = xp[s1];
    *(float2*)(gated + (size_t)idx * 2) = v;
}

extern "C" void kernel_launch(void* const* d_in, const int* in_sizes, int n_in,
                              void* d_out, int out_size, void* d_ws, size_t ws_size,
                              hipStream_t stream)
{
    const float* x     = (const float*)d_in[0];
    const float* total = (const float*)d_in[1];
    const float* gw1 = (const float*)d_in[2];
    const float* g1  = (const float*)d_in[3];
    const float* b1  = (const float*)d_in[4];
    const float* gw2 = (const float*)d_in[5];
    const float* g2  = (const float*)d_in[6];
    const float* b2  = (const float*)d_in[7];
    const float* gw3 = (const float*)d_in[8];
    const float* g3  = (const float*)d_in[9];
    const float* b3  = (const float*)d_in[10];
    const float* gw4 = (const float*)d_in[11];
    const float* g4  = (const float*)d_in[12];
    const float* b4  = (const float*)d_in[13];
    const float* fw1 = (const float*)d_in[14];
    const float* fb1 = (const float*)d_in[15];
    const float* g1d = (const float*)d_in[16];
    const float* b1d = (const float*)d_in[17];
    const float* fw2 = (const float*)d_in[18];
    const float* fb2 = (const float*)d_in[19];
    const float* cw1 = (const float*)d_in[20];

    char* ws = (char*)d_ws;
    size_t off = 0;
    auto alloc = [&](size_t bytes) { void* p = ws + off; off = (off + bytes + 255) & ~(size_t)255; return p; };
    ushort* h1n = (ushort*)alloc((size_t)40796160 * 2); // NHWC [64][40][498][32]
    ushort* h2n = (ushort*)alloc((size_t)9994240 * 2);  // NHWC [64][20][122][64]
    ushort* h3n = (ushort*)alloc((size_t)2293760 * 2);  // NHWC [64][10][28][128]
    float* h4t   = (float*)alloc((size_t)409600 * 4);   // [1600][256]
    int*   sel   = (int*)alloc(512);
    float* gated = (float*)alloc((size_t)4096000 * 4);  // [64,80,800]
    float* wt1 = (float*)alloc((size_t)2400 * 4);
    float* wt5 = (float*)alloc((size_t)6272 * 4);
    ushort* wp2 = (ushort*)alloc((size_t)153600 * 2);   // [75][64][32]
    ushort* wp3 = (ushort*)alloc((size_t)614400 * 2);   // [75][128][64]
    // aliases into dead regions (safe by launch order):
    ushort* A4  = (ushort*)h1n;  // 30.7MB <= 81.6MB; h1 dead after conv2
    ushort* w4p = (ushort*)h2n;  // 4.9MB  <= 20MB;   h2 dead after conv3

    float* outc = (float*)d_out;            // [64,64,40,397]
    float* rw   = outc + (size_t)65044480;  // [64,5]

    // weight prep
    wtrans_k<<<(32 * 75 + 255) / 256, 256, 0, stream>>>(gw1, wt1, 32, 75);
    wtrans_k<<<(64 * 98 + 255) / 256, 256, 0, stream>>>(cw1, wt5, 64, 98);
    wperm_k<<<(153600 + 255) / 256, 256, 0, stream>>>(gw2, wp2, 64, 32, 75);
    wperm_k<<<(614400 + 255) / 256, 256, 0, stream>>>(gw3, wp3, 128, 64, 75);

    // L1: VALU conv, NHWC bf16 out
    conv_tile<float, __hip_bfloat16, true, true, 5, 15, 2, 4, 4, 4, 128>
        <<<8 * 40 * 64, 128, (1336 + 2400) * 4, stream>>>(
        total, wt1, g1, b1, (__hip_bfloat16*)h1n, 1, 80, 2000, 32, 40, 498, 2, 2, 8, 1);

    // L2: implicit-GEMM MFMA. M_BLK=64 (2 tiles over OW=122), OC=64, IC=32, waves 2x2.
    convmm_k<64, 64, 32, 1, 2, 2><<<64 * 20 * 2, 256, 0, stream>>>(
        h1n, wp2, g2, b2, h2n, 40, 498, 20, 122, 2);

    // L3: M_BLK=32 (OW=28), OC=128, IC=64 (2 chunks), waves 1x4.
    convmm_k<32, 128, 64, 2, 1, 4><<<64 * 10 * 1, 256, 0, stream>>>(
        h2n, wp3, g3, b3, h3n, 20, 122, 10, 28, 1);

    // L4: im2col + MFMA GEMM (h1/h2 regions dead now)
    wperm4_k<<<(2457600 + 255) / 256, 256, 0, stream>>>(gw4, w4p);
    im2col4_k<<<(15360000 + 255) / 256, 256, 0, stream>>>(h3n, A4);
    gemm4_k<<<100, 256, 0, stream>>>(A4, w4p, g4, b4, h4t);

    route_k<<<64, 256, 0, stream>>>(h4t, fw1, fb1, g1d, b1d, fw2, fb2, rw, sel);
    gather_k<<<8000, 256, 0, stream>>>(x, sel, gated);

    // L5 stem: VALU conv, NCHW f32 out
    conv_tile<float, float, false, false, 7, 14, 2, 2, 8, 4, 128>
        <<<7 * 40 * 64, 128, (980 + 6272) * 4, stream>>>(
        gated, wt5, nullptr, nullptr, outc, 1, 80, 800, 64, 40, 397, 3, 3, 7, 1);
}

// Round 5
// 599.984 us; speedup vs baseline: 48.8664x; 1.4231x over previous
//
#include <hip/hip_runtime.h>
#include <hip/hip_bf16.h>

#define DEV __device__ __forceinline__

typedef __attribute__((ext_vector_type(8))) short short8_t;
typedef __attribute__((ext_vector_type(4))) float f32x4;

DEV float gelu_erf(float x) { return 0.5f * x * (1.0f + erff(x * 0.70710678118654752440f)); }

// ---------- weight prep ----------
// gwX [OC][IC][KH][KW] f32 -> wp [KH*KW][OC][IC] bf16  (conv2/conv3)
__global__ void wperm_k(const float* __restrict__ w, ushort* __restrict__ wp,
                        int OC, int IC, int KC) {
    int idx = blockIdx.x * blockDim.x + threadIdx.x;
    if (idx >= KC * OC * IC) return;
    int ic = idx % IC, t = idx / IC;
    int oc = t % OC, kc = t / OC;
    __hip_bfloat16 v = __float2bfloat16(w[((size_t)oc * IC + ic) * KC + kc]);
    wp[idx] = *(ushort*)&v;
}

// gw4 [256][128][5][15] f32 -> w4p [256][(kh*15+kw)*128+ic] bf16
__global__ void wperm4_k(const float* __restrict__ w, ushort* __restrict__ wp) {
    int idx = blockIdx.x * blockDim.x + threadIdx.x;
    if (idx >= 256 * 9600) return;
    int kp = idx % 9600, oc = idx / 9600;
    int ic = kp & 127, kc = kp >> 7;
    __hip_bfloat16 v = __float2bfloat16(w[((size_t)oc * 128 + ic) * 75 + kc]);
    wp[idx] = *(ushort*)&v;
}

// gw1 [32][1][5][15] -> wp1[32][96], k = kh*16+kw (kw=15 zero, kh padded to 6)
__global__ void wperm1_k(const float* __restrict__ w, ushort* __restrict__ wp) {
    int idx = blockIdx.x * blockDim.x + threadIdx.x;
    if (idx >= 32 * 96) return;
    int oc = idx / 96, k = idx % 96;
    int kh = k >> 4, kw = k & 15;
    float v = (kh < 5 && kw < 15) ? w[oc * 75 + kh * 15 + kw] : 0.f;
    __hip_bfloat16 h = __float2bfloat16(v);
    wp[idx] = *(ushort*)&h;
}

// cw1 [64][1][7][14] -> wp5[64][128], k = kh*16 + a*2 + c, kw = 2a+c-1
__global__ void wperm5_k(const float* __restrict__ w, ushort* __restrict__ wp) {
    int idx = blockIdx.x * blockDim.x + threadIdx.x;
    if (idx >= 64 * 128) return;
    int oc = idx >> 7, k = idx & 127;
    int kh = k >> 4, t = k & 15;
    int a = t >> 1, c = t & 1, kw = 2 * a + c - 1;
    float v = (kh < 7 && kw >= 0 && kw < 14) ? w[oc * 98 + kh * 14 + kw] : 0.f;
    __hip_bfloat16 h = __float2bfloat16(v);
    wp[idx] = *(ushort*)&h;
}

// ---------- IC=1 implicit-GEMM MFMA conv (conv1, conv5) ----------
// K = rows(2*NCH) x 16 taps; per-lane A-frags built from LDS rows via 4x b32;
// B (weights) fully preloaded in registers. SH=2 fixed.
template <int M_BLK, int NOC, int NCH, int NWM, int NWN, int ST, bool F32IN, bool BNG>
__global__ __launch_bounds__(64 * NWM * NWN) void convmm1_k(
    const void* __restrict__ in_, const ushort* __restrict__ wp,
    const float* __restrict__ gamma, const float* __restrict__ beta,
    void* __restrict__ out_,
    int IH, int IWE,        // input rows; row length (f32 elems | u32 pairs)
    int OH, int OW, int NOWT, int PH)
{
    constexpr int NT = 64 * NWM * NWN;
    constexpr int NR = 2 * NCH;
    constexpr int SPAN = (M_BLK - 1) * ST + 16;
    constexpr int SSTR = ((SPAN + 7) & ~7) + 2;       // ushort units, even
    constexpr int STAGE_B = NR * SSTR * 2;
    constexpr int TILE_B = BNG ? (M_BLK * NOC * 2) : (NOC * M_BLK * 4);
    constexpr int SMEM_B = STAGE_B > TILE_B ? STAGE_B : TILE_B;
    __shared__ __align__(16) char smem[SMEM_B];
    ushort* stg = (ushort*)smem;

    int bid = blockIdx.x;
    const int owt = bid % NOWT; bid /= NOWT;
    const int oh = bid % OH;
    const int b  = bid / OH;
    const int ow0 = owt * M_BLK;
    const int tid = threadIdx.x;
    const int w = tid >> 6, l = tid & 63;
    const int wn = w % NWN, wm = w / NWN;
    const int m_wave = wm * 32, n_wave = wn * 32;
    const int lc = l & 15, lr = l >> 4;

    // ---- stage NR rows (bf16, zero-padded) ----
    if (F32IN) {
        for (int u = tid; u < NR * SPAN; u += NT) {
            int r = u / SPAN, e = u - r * SPAN;
            int ih = oh * 2 - PH + r;
            int iw = ow0 * ST - 2 + e;
            float v = 0.f;
            if ((unsigned)ih < (unsigned)IH && (unsigned)iw < (unsigned)IWE)
                v = ((const float*)in_)[((size_t)b * IH + ih) * IWE + iw];
            __hip_bfloat16 h = __float2bfloat16(v);
            stg[r * SSTR + e] = *(ushort*)&h;
        }
    } else {
        constexpr int SPANU = SPAN / 2;
        for (int u = tid; u < NR * SPANU; u += NT) {
            int r = u / SPANU, e = u - r * SPANU;
            int ih = oh * 2 - PH + r;
            int iu = ow0 - 2 + e;
            uint v = 0;
            if ((unsigned)ih < (unsigned)IH && (unsigned)iu < (unsigned)IWE)
                v = ((const uint*)in_)[((size_t)b * IH + ih) * IWE + iu];
            *(uint*)&stg[r * SSTR + e * 2] = v;
        }
    }

    // ---- preload all B fragments in registers ----
    short8_t bfr[NCH][2];
    {
        const ushort* wb = wp + (size_t)(n_wave + lc) * (NCH * 32) + lr * 8;
#pragma unroll
        for (int cc = 0; cc < NCH; ++cc)
#pragma unroll
            for (int nj = 0; nj < 2; ++nj)
                bfr[cc][nj] = *(const short8_t*)(wb + (size_t)nj * 16 * (NCH * 32) + cc * 32);
    }

    __syncthreads();

    f32x4 acc[2][2];
#pragma unroll
    for (int i = 0; i < 2; ++i)
#pragma unroll
        for (int j = 0; j < 2; ++j) acc[i][j] = (f32x4){0.f, 0.f, 0.f, 0.f};

#pragma unroll
    for (int cc = 0; cc < NCH; ++cc) {
        const int kh = 2 * cc + (lr >> 1);
        const uint* lrow = (const uint*)&stg[kh * SSTR];
        short8_t a[2];
#pragma unroll
        for (int mi = 0; mi < 2; ++mi) {
            const int m = m_wave + mi * 16 + lc;
            const int half = (m * ST + (lr & 1) * 8) >> 1;
            union { uint u[4]; short8_t s; } av;
            av.u[0] = lrow[half];
            av.u[1] = lrow[half + 1];
            av.u[2] = lrow[half + 2];
            av.u[3] = lrow[half + 3];
            a[mi] = av.s;
        }
#pragma unroll
        for (int mi = 0; mi < 2; ++mi)
#pragma unroll
            for (int nj = 0; nj < 2; ++nj)
                acc[mi][nj] = __builtin_amdgcn_mfma_f32_16x16x32_bf16(a[mi], bfr[cc][nj], acc[mi][nj], 0, 0, 0);
    }

    __syncthreads();   // staging rows dead; smem reused for output tile

    if (BNG) {
        // NHWC bf16 out with BN+GELU, LDS restage for contiguous store
        ushort* tile = (ushort*)smem;                 // [M_BLK][NOC]
#pragma unroll
        for (int nj = 0; nj < 2; ++nj) {
            const int n = n_wave + nj * 16 + lc;
            const float s = gamma[n] * rsqrtf(1.0f + 1e-5f);
            const float bb = beta[n];
#pragma unroll
            for (int mi = 0; mi < 2; ++mi)
#pragma unroll
                for (int r = 0; r < 4; ++r) {
                    const int m = m_wave + mi * 16 + lr * 4 + r;
                    float y = gelu_erf(fmaf(acc[mi][nj][r], s, bb));
                    __hip_bfloat16 h = __float2bfloat16(y);
                    tile[m * NOC + n] = *(ushort*)&h;
                }
        }
        __syncthreads();
        const int mv = min(M_BLK, OW - ow0);
        uint* dst = (uint*)((ushort*)out_ + (((size_t)b * OH + oh) * OW + ow0) * NOC);
        const uint* src = (const uint*)tile;
        for (int idx = tid; idx < mv * NOC / 2; idx += NT) dst[idx] = src[idx];
    } else {
        // NCHW f32 out, LDS restage: [NOC][M_BLK]
        float* tile = (float*)smem;
#pragma unroll
        for (int nj = 0; nj < 2; ++nj) {
            const int n = n_wave + nj * 16 + lc;
#pragma unroll
            for (int mi = 0; mi < 2; ++mi)
#pragma unroll
                for (int r = 0; r < 4; ++r) {
                    const int m = m_wave + mi * 16 + lr * 4 + r;
                    tile[n * M_BLK + m] = acc[mi][nj][r];
                }
        }
        __syncthreads();
        const int mv = min(M_BLK, OW - ow0);
        float* outb = (float*)out_ + ((size_t)b * NOC * OH + oh) * OW + ow0;
        for (int idx = tid; idx < NOC * mv; idx += NT) {
            int oc = idx / mv, j = idx - oc * mv;
            outb[(size_t)oc * OH * OW + j] = tile[oc * M_BLK + j];
        }
    }
}

// ---------- implicit-GEMM MFMA conv (NHWC bf16 -> NHWC bf16), conv2/conv3 ----------
template <int M_BLK, int OC, int ICT, int NICC, int NWM, int NWN>
__global__ __launch_bounds__(64 * NWM * NWN) void convmm_k(
    const ushort* __restrict__ in, const ushort* __restrict__ wp,
    const float* __restrict__ gamma, const float* __restrict__ beta,
    ushort* __restrict__ out,
    int IH, int IW, int OH, int OW, int NOWT)
{
    constexpr int KH = 5, KW = 15, SW = 4;
    constexpr int SPAN = (M_BLK - 1) * SW + KW;
    constexpr int ICB = ICT * 2;
    constexpr int NSL = ICT / 8;
    constexpr int KEYM = NSL - 1;
    constexpr int NT = 64 * NWM * NWN;
    constexpr int NUNITS = SPAN * NSL;

    __shared__ __align__(16) ushort Abuf[2][SPAN * ICT];

    int bid = blockIdx.x;
    const int owt = bid % NOWT; bid /= NOWT;
    const int oh  = bid % OH;
    const int b   = bid / OH;
    const int ow0 = owt * M_BLK;
    const int tid = threadIdx.x;
    const int w = tid >> 6, l = tid & 63;
    const int wn = w % NWN, wm = w / NWN;
    const int m_wave = wm * 32, n_wave = wn * 32;
    const int lc = l & 15, lr = l >> 4;

    const int ih0 = oh * 2 - 2;
    const int iw0 = ow0 * SW - 2;
    const ushort* inb = in + (size_t)b * IH * IW * ICT;

    f32x4 acc[2][2];
#pragma unroll
    for (int i = 0; i < 2; ++i)
#pragma unroll
        for (int j = 0; j < 2; ++j) acc[i][j] = (f32x4){0.f, 0.f, 0.f, 0.f};

    auto stage = [&](int kh, int buf) {
        const int ih = ih0 + kh;
        char* dst = (char*)Abuf[buf];
        if ((unsigned)ih < (unsigned)IH) {
            const ushort* src = inb + (size_t)ih * IW * ICT;
            for (int u = tid; u < NUNITS; u += NT) {
                int p = u / NSL, sl = u - p * NSL;
                int iw = iw0 + p;
                uint4 v = {0u, 0u, 0u, 0u};
                if ((unsigned)iw < (unsigned)IW)
                    v = *(const uint4*)(src + (size_t)iw * ICT + sl * 8);
                *(uint4*)(dst + p * ICB + ((sl ^ ((p >> 2) & KEYM)) << 4)) = v;
            }
        } else {
            for (int u = tid; u < NUNITS; u += NT) {
                int p = u / NSL, sl = u - p * NSL;
                *(uint4*)(dst + p * ICB + ((sl ^ ((p >> 2) & KEYM)) << 4)) = (uint4){0u, 0u, 0u, 0u};
            }
        }
    };

    stage(0, 0);
#pragma unroll 1
    for (int kh = 0; kh < KH; ++kh) {
        __syncthreads();
        if (kh + 1 < KH) stage(kh + 1, (kh + 1) & 1);
        const char* buf = (const char*)Abuf[kh & 1];
#pragma unroll 1
        for (int kw = 0; kw < KW; ++kw) {
#pragma unroll
            for (int icc = 0; icc < NICC; ++icc) {
                short8_t a[2], bf[2];
#pragma unroll
                for (int mi = 0; mi < 2; ++mi) {
                    const int r = m_wave + mi * 16 + lc;
                    const int p = SW * r + kw;
                    const int sl = icc * 4 + lr;
                    a[mi] = *(const short8_t*)(buf + p * ICB + ((sl ^ ((p >> 2) & KEYM)) << 4));
                }
                const ushort* wb = wp + ((size_t)(kh * KW + kw) * OC + n_wave + lc) * ICT + icc * 32 + lr * 8;
#pragma unroll
                for (int nj = 0; nj < 2; ++nj)
                    bf[nj] = *(const short8_t*)(wb + nj * 16 * ICT);
#pragma unroll
                for (int mi = 0; mi < 2; ++mi)
#pragma unroll
                    for (int nj = 0; nj < 2; ++nj)
                        acc[mi][nj] = __builtin_amdgcn_mfma_f32_16x16x32_bf16(a[mi], bf[nj], acc[mi][nj], 0, 0, 0);
            }
        }
    }

    ushort* outb = out + ((size_t)b * OH + oh) * OW * OC;
#pragma unroll
    for (int nj = 0; nj < 2; ++nj) {
        const int n = n_wave + nj * 16 + lc;
        const float s = gamma[n] * rsqrtf(1.0f + 1e-5f);
        const float bb = beta[n];
#pragma unroll
        for (int mi = 0; mi < 2; ++mi) {
#pragma unroll
            for (int r = 0; r < 4; ++r) {
                const int m = m_wave + mi * 16 + lr * 4 + r;
                const int ow = ow0 + m;
                if (ow < OW) {
                    float y = gelu_erf(fmaf(acc[mi][nj][r], s, bb));
                    __hip_bfloat16 h = __float2bfloat16(y);
                    outb[(size_t)ow * OC + n] = *(ushort*)&h;
                }
            }
        }
    }
}

// ---------- conv4: im2col + MFMA GEMM ----------
__global__ void im2col4_k(const ushort* __restrict__ h3, ushort* __restrict__ A) {
    int idx = blockIdx.x * blockDim.x + threadIdx.x;
    if (idx >= 1600 * 9600) return;
    int kp = idx % 9600, m = idx / 9600;
    int ic = kp & 127, kc = kp >> 7;
    int b = m / 25, p = m - b * 25;
    int oh = p / 5, ow = p - oh * 5;
    int kh = kc / 15, kw = kc - kh * 15;
    int ih = oh * 2 - 2 + kh, iw = ow * 4 - 2 + kw;
    ushort v = 0;
    if ((unsigned)ih < 10u && (unsigned)iw < 28u)
        v = h3[(((size_t)b * 10 + ih) * 28 + iw) * 128 + ic];
    A[idx] = v;
}

__global__ __launch_bounds__(256) void gemm4_k(
    const ushort* __restrict__ A, const ushort* __restrict__ B,
    const float* __restrict__ gamma, const float* __restrict__ beta,
    float* __restrict__ C)
{
    __shared__ ushort Al[64 * 32];
    __shared__ ushort Bl[64 * 32];
    const int nt = blockIdx.x & 3, mt = blockIdx.x >> 2;
    const int m0 = mt * 64, n0 = nt * 64;
    const int tid = threadIdx.x;
    const int w = tid >> 6, l = tid & 63;
    const int wr = (w >> 1) * 32, wc = (w & 1) * 32;
    const int lc = l & 15, lr = l >> 4;

    f32x4 acc[2][2];
#pragma unroll
    for (int i = 0; i < 2; ++i)
#pragma unroll
        for (int j = 0; j < 2; ++j) acc[i][j] = (f32x4){0.f, 0.f, 0.f, 0.f};

    const int arow = 16 * w + (l >> 2);
    const int acol8 = (l & 3) * 8;
    const ushort* ga = A + (size_t)(m0 + arow) * 9600 + acol8;
    const ushort* gb = B + (size_t)(n0 + arow) * 9600 + acol8;

    for (int kc = 0; kc < 300; ++kc) {
        __syncthreads();
        __builtin_amdgcn_global_load_lds(ga + kc * 32, &Al[16 * w * 32], 16, 0, 0);
        __builtin_amdgcn_global_load_lds(gb + kc * 32, &Bl[16 * w * 32], 16, 0, 0);
        __syncthreads();
        short8_t a0 = *(const short8_t*)&Al[(wr + lc) * 32 + 8 * lr];
        short8_t a1 = *(const short8_t*)&Al[(wr + 16 + lc) * 32 + 8 * lr];
        short8_t b0 = *(const short8_t*)&Bl[(wc + lc) * 32 + 8 * lr];
        short8_t b1 = *(const short8_t*)&Bl[(wc + 16 + lc) * 32 + 8 * lr];
        acc[0][0] = __builtin_amdgcn_mfma_f32_16x16x32_bf16(a0, b0, acc[0][0], 0, 0, 0);
        acc[0][1] = __builtin_amdgcn_mfma_f32_16x16x32_bf16(a0, b1, acc[0][1], 0, 0, 0);
        acc[1][0] = __builtin_amdgcn_mfma_f32_16x16x32_bf16(a1, b0, acc[1][0], 0, 0, 0);
        acc[1][1] = __builtin_amdgcn_mfma_f32_16x16x32_bf16(a1, b1, acc[1][1], 0, 0, 0);
    }

#pragma unroll
    for (int mi = 0; mi < 2; ++mi)
#pragma unroll
        for (int nj = 0; nj < 2; ++nj) {
            const int n = n0 + wc + 16 * nj + lc;
            const float s = gamma[n] * rsqrtf(1.0f + 1e-5f);
            const float bb = beta[n];
#pragma unroll
            for (int r = 0; r < 4; ++r) {
                const int m = m0 + wr + 16 * mi + 4 * lr + r;
                C[(size_t)m * 256 + n] = gelu_erf(fmaf(acc[mi][nj][r], s, bb));
            }
        }
}

// ---------- routing head ----------
__global__ void route_k(const float* __restrict__ h4t,
                        const float* __restrict__ fw1, const float* __restrict__ fb1,
                        const float* __restrict__ g1d, const float* __restrict__ b1d,
                        const float* __restrict__ fw2, const float* __restrict__ fb2,
                        float* __restrict__ rw_out, int* __restrict__ sel_out)
{
    __shared__ float pooled[256];
    __shared__ float hmid[32];
    __shared__ float rwv[5];
    const int b = blockIdx.x, c = threadIdx.x;
    const float* p = h4t + (size_t)b * 25 * 256 + c;
    float sum = 0.f;
#pragma unroll
    for (int i = 0; i < 25; ++i) sum += p[i * 256];
    pooled[c] = sum * (1.0f / 25.0f);
    __syncthreads();
    if (c < 32) {
        float a = fb1[c];
        const float* wr = fw1 + c * 256;
        for (int i = 0; i < 256; ++i) a += pooled[i] * wr[i];
        a = gelu_erf(a);
        a = a * (g1d[c] * rsqrtf(1.0f + 1e-5f)) + b1d[c];
        hmid[c] = a;
    }
    __syncthreads();
    if (c < 5) {
        float a = fb2[c];
        const float* wr = fw2 + c * 32;
#pragma unroll
        for (int i = 0; i < 32; ++i) a += hmid[i] * wr[i];
        rwv[c] = a;
        rw_out[b * 5 + c] = a;
    }
    __syncthreads();
    if (c == 0) {
        int i1 = 0;
        for (int i = 1; i < 5; ++i) if (rwv[i] > rwv[i1]) i1 = i;
        int i2 = -1;
        for (int i = 0; i < 5; ++i) {
            if (i == i1) continue;
            if (i2 < 0 || rwv[i] > rwv[i2]) i2 = i;
        }
        sel_out[b * 2]     = i1 < i2 ? i1 : i2;
        sel_out[b * 2 + 1] = i1 < i2 ? i2 : i1;
    }
}

// gather -> packed bf16 pairs: gated[b][f][t] = (bf16(x[..sel0]), bf16(x[..sel1]))
__global__ void gather_k(const float* __restrict__ x, const int* __restrict__ sel,
                         uint* __restrict__ gated)
{
    const int idx = blockIdx.x * blockDim.x + threadIdx.x; // B*80*400
    const int b = idx / 32000;
    const int s0 = sel[b * 2], s1 = sel[b * 2 + 1];
    const float* xp = x + (size_t)idx * 5;
    __hip_bfloat16 h0 = __float2bfloat16(xp[s0]);
    __hip_bfloat16 h1 = __float2bfloat16(xp[s1]);
    gated[idx] = (uint)*(ushort*)&h0 | ((uint)*(ushort*)&h1 << 16);
}

extern "C" void kernel_launch(void* const* d_in, const int* in_sizes, int n_in,
                              void* d_out, int out_size, void* d_ws, size_t ws_size,
                              hipStream_t stream)
{
    const float* x     = (const float*)d_in[0];
    const float* total = (const float*)d_in[1];
    const float* gw1 = (const float*)d_in[2];
    const float* g1  = (const float*)d_in[3];
    const float* b1  = (const float*)d_in[4];
    const float* gw2 = (const float*)d_in[5];
    const float* g2  = (const float*)d_in[6];
    const float* b2  = (const float*)d_in[7];
    const float* gw3 = (const float*)d_in[8];
    const float* g3  = (const float*)d_in[9];
    const float* b3  = (const float*)d_in[10];
    const float* gw4 = (const float*)d_in[11];
    const float* g4  = (const float*)d_in[12];
    const float* b4  = (const float*)d_in[13];
    const float* fw1 = (const float*)d_in[14];
    const float* fb1 = (const float*)d_in[15];
    const float* g1d = (const float*)d_in[16];
    const float* b1d = (const float*)d_in[17];
    const float* fw2 = (const float*)d_in[18];
    const float* fb2 = (const float*)d_in[19];
    const float* cw1 = (const float*)d_in[20];

    char* ws = (char*)d_ws;
    size_t off = 0;
    auto alloc = [&](size_t bytes) { void* p = ws + off; off = (off + bytes + 255) & ~(size_t)255; return p; };
    ushort* h1n = (ushort*)alloc((size_t)40796160 * 2); // NHWC [64][40][498][32]
    ushort* h2n = (ushort*)alloc((size_t)9994240 * 2);  // NHWC [64][20][122][64]
    ushort* h3n = (ushort*)alloc((size_t)2293760 * 2);  // NHWC [64][10][28][128]
    float* h4t   = (float*)alloc((size_t)409600 * 4);   // [1600][256]
    int*   sel   = (int*)alloc(512);
    uint*  gated = (uint*)alloc((size_t)2048000 * 4);   // [64][80][400] packed bf16x2
    ushort* wp1 = (ushort*)alloc((size_t)32 * 96 * 2);
    ushort* wp2 = (ushort*)alloc((size_t)153600 * 2);   // [75][64][32]
    ushort* wp3 = (ushort*)alloc((size_t)614400 * 2);   // [75][128][64]
    ushort* wp5 = (ushort*)alloc((size_t)64 * 128 * 2);
    // aliases into dead regions (safe by launch order):
    ushort* A4  = (ushort*)h1n;  // 30.7MB <= 81.6MB; h1 dead after conv2
    ushort* w4p = (ushort*)h2n;  // 4.9MB  <= 20MB;   h2 dead after conv3

    float* outc = (float*)d_out;            // [64,64,40,397]
    float* rw   = outc + (size_t)65044480;  // [64,5]

    // weight prep
    wperm1_k<<<(32 * 96 + 255) / 256, 256, 0, stream>>>(gw1, wp1);
    wperm5_k<<<(64 * 128 + 255) / 256, 256, 0, stream>>>(cw1, wp5);
    wperm_k<<<(153600 + 255) / 256, 256, 0, stream>>>(gw2, wp2, 64, 32, 75);
    wperm_k<<<(614400 + 255) / 256, 256, 0, stream>>>(gw3, wp3, 128, 64, 75);

    // L1: MFMA IC=1 conv. M_BLK=128, NOC=32, K=96 (3 chunks), ST=4, f32 in, BN+GELU NHWC out.
    convmm1_k<128, 32, 3, 4, 1, 4, true, true><<<64 * 40 * 4, 256, 0, stream>>>(
        total, wp1, g1, b1, h1n, 80, 2000, 40, 498, 4, 2);

    // L2: implicit-GEMM MFMA. M_BLK=64, OC=64, IC=32, waves 2x2.
    convmm_k<64, 64, 32, 1, 2, 2><<<64 * 20 * 2, 256, 0, stream>>>(
        h1n, wp2, g2, b2, h2n, 40, 498, 20, 122, 2);

    // L3: M_BLK=32, OC=128, IC=64 (2 chunks), waves 1x4.
    convmm_k<32, 128, 64, 2, 1, 4><<<64 * 10 * 1, 256, 0, stream>>>(
        h2n, wp3, g3, b3, h3n, 20, 122, 10, 28, 1);

    // L4: im2col + MFMA GEMM
    wperm4_k<<<(2457600 + 255) / 256, 256, 0, stream>>>(gw4, w4p);
    im2col4_k<<<(15360000 + 255) / 256, 256, 0, stream>>>(h3n, A4);
    gemm4_k<<<100, 256, 0, stream>>>(A4, w4p, g4, b4, h4t);

    route_k<<<64, 256, 0, stream>>>(h4t, fw1, fb1, g1d, b1d, fw2, fb2, rw, sel);
    gather_k<<<8000, 256, 0, stream>>>(x, sel, gated);

    // L5: MFMA IC=1 conv via (t,s) factorization. M_BLK=64, NOC=64, K=128 (4 chunks), ST=2.
    convmm1_k<64, 64, 4, 2, 2, 2, false, false><<<64 * 40 * 7, 256, 0, stream>>>(
        gated, wp5, nullptr, nullptr, outc, 80, 400, 40, 397, 7, 3);
}

// Round 6
// 566.833 us; speedup vs baseline: 51.7243x; 1.0585x over previous
//
#include <hip/hip_runtime.h>
#include <hip/hip_bf16.h>

#define DEV __device__ __forceinline__

typedef __attribute__((ext_vector_type(8))) short short8_t;
typedef __attribute__((ext_vector_type(4))) float f32x4;

DEV float gelu_erf(float x) { return 0.5f * x * (1.0f + erff(x * 0.70710678118654752440f)); }

// ---------- weight prep ----------
// gwX [OC][IC][KH][KW] f32 -> wp [KH*KW][OC][IC] bf16  (conv2/conv3)
__global__ void wperm_k(const float* __restrict__ w, ushort* __restrict__ wp,
                        int OC, int IC, int KC) {
    int idx = blockIdx.x * blockDim.x + threadIdx.x;
    if (idx >= KC * OC * IC) return;
    int ic = idx % IC, t = idx / IC;
    int oc = t % OC, kc = t / OC;
    __hip_bfloat16 v = __float2bfloat16(w[((size_t)oc * IC + ic) * KC + kc]);
    wp[idx] = *(ushort*)&v;
}

// gw4 [256][128][5][15] f32 -> w4p [256][(kh*15+kw)*128+ic] bf16
__global__ void wperm4_k(const float* __restrict__ w, ushort* __restrict__ wp) {
    int idx = blockIdx.x * blockDim.x + threadIdx.x;
    if (idx >= 256 * 9600) return;
    int kp = idx % 9600, oc = idx / 9600;
    int ic = kp & 127, kc = kp >> 7;
    __hip_bfloat16 v = __float2bfloat16(w[((size_t)oc * 128 + ic) * 75 + kc]);
    wp[idx] = *(ushort*)&v;
}

// gw1 [32][1][5][15] -> wp1[32][96], k = kh*16+kw (kw=15 zero, kh padded to 6)
__global__ void wperm1_k(const float* __restrict__ w, ushort* __restrict__ wp) {
    int idx = blockIdx.x * blockDim.x + threadIdx.x;
    if (idx >= 32 * 96) return;
    int oc = idx / 96, k = idx % 96;
    int kh = k >> 4, kw = k & 15;
    float v = (kh < 5 && kw < 15) ? w[oc * 75 + kh * 15 + kw] : 0.f;
    __hip_bfloat16 h = __float2bfloat16(v);
    wp[idx] = *(ushort*)&h;
}

// cw1 [64][1][7][14] -> wp5[64][128], k = kh*16 + a*2 + c, kw = 2a+c-1
__global__ void wperm5_k(const float* __restrict__ w, ushort* __restrict__ wp) {
    int idx = blockIdx.x * blockDim.x + threadIdx.x;
    if (idx >= 64 * 128) return;
    int oc = idx >> 7, k = idx & 127;
    int kh = k >> 4, t = k & 15;
    int a = t >> 1, c = t & 1, kw = 2 * a + c - 1;
    float v = (kh < 7 && kw >= 0 && kw < 14) ? w[oc * 98 + kh * 14 + kw] : 0.f;
    __hip_bfloat16 h = __float2bfloat16(v);
    wp[idx] = *(ushort*)&h;
}

// ---------- IC=1 implicit-GEMM MFMA conv (conv1, conv5) ----------
template <int M_BLK, int NOC, int NCH, int NWM, int NWN, int ST, bool F32IN, bool BNG>
__global__ __launch_bounds__(64 * NWM * NWN) void convmm1_k(
    const void* __restrict__ in_, const ushort* __restrict__ wp,
    const float* __restrict__ gamma, const float* __restrict__ beta,
    void* __restrict__ out_,
    int IH, int IWE, int OH, int OW, int NOWT, int PH)
{
    constexpr int NT = 64 * NWM * NWN;
    constexpr int NR = 2 * NCH;
    constexpr int SPAN = (M_BLK - 1) * ST + 16;
    constexpr int SSTR = ((SPAN + 7) & ~7) + 2;
    constexpr int STAGE_B = NR * SSTR * 2;
    constexpr int TILE_B = BNG ? (M_BLK * NOC * 2) : (NOC * M_BLK * 4);
    constexpr int SMEM_B = STAGE_B > TILE_B ? STAGE_B : TILE_B;
    __shared__ __align__(16) char smem[SMEM_B];
    ushort* stg = (ushort*)smem;

    int bid = blockIdx.x;
    const int owt = bid % NOWT; bid /= NOWT;
    const int oh = bid % OH;
    const int b  = bid / OH;
    const int ow0 = owt * M_BLK;
    const int tid = threadIdx.x;
    const int w = tid >> 6, l = tid & 63;
    const int wn = w % NWN, wm = w / NWN;
    const int m_wave = wm * 32, n_wave = wn * 32;
    const int lc = l & 15, lr = l >> 4;

    if (F32IN) {
        for (int u = tid; u < NR * SPAN; u += NT) {
            int r = u / SPAN, e = u - r * SPAN;
            int ih = oh * 2 - PH + r;
            int iw = ow0 * ST - 2 + e;
            float v = 0.f;
            if ((unsigned)ih < (unsigned)IH && (unsigned)iw < (unsigned)IWE)
                v = ((const float*)in_)[((size_t)b * IH + ih) * IWE + iw];
            __hip_bfloat16 h = __float2bfloat16(v);
            stg[r * SSTR + e] = *(ushort*)&h;
        }
    } else {
        constexpr int SPANU = SPAN / 2;
        for (int u = tid; u < NR * SPANU; u += NT) {
            int r = u / SPANU, e = u - r * SPANU;
            int ih = oh * 2 - PH + r;
            int iu = ow0 - 2 + e;
            uint v = 0;
            if ((unsigned)ih < (unsigned)IH && (unsigned)iu < (unsigned)IWE)
                v = ((const uint*)in_)[((size_t)b * IH + ih) * IWE + iu];
            *(uint*)&stg[r * SSTR + e * 2] = v;
        }
    }

    short8_t bfr[NCH][2];
    {
        const ushort* wb = wp + (size_t)(n_wave + lc) * (NCH * 32) + lr * 8;
#pragma unroll
        for (int cc = 0; cc < NCH; ++cc)
#pragma unroll
            for (int nj = 0; nj < 2; ++nj)
                bfr[cc][nj] = *(const short8_t*)(wb + (size_t)nj * 16 * (NCH * 32) + cc * 32);
    }

    __syncthreads();

    f32x4 acc[2][2];
#pragma unroll
    for (int i = 0; i < 2; ++i)
#pragma unroll
        for (int j = 0; j < 2; ++j) acc[i][j] = (f32x4){0.f, 0.f, 0.f, 0.f};

#pragma unroll
    for (int cc = 0; cc < NCH; ++cc) {
        const int kh = 2 * cc + (lr >> 1);
        const uint* lrow = (const uint*)&stg[kh * SSTR];
        short8_t a[2];
#pragma unroll
        for (int mi = 0; mi < 2; ++mi) {
            const int m = m_wave + mi * 16 + lc;
            const int half = (m * ST + (lr & 1) * 8) >> 1;
            union { uint u[4]; short8_t s; } av;
            av.u[0] = lrow[half];
            av.u[1] = lrow[half + 1];
            av.u[2] = lrow[half + 2];
            av.u[3] = lrow[half + 3];
            a[mi] = av.s;
        }
#pragma unroll
        for (int mi = 0; mi < 2; ++mi)
#pragma unroll
            for (int nj = 0; nj < 2; ++nj)
                acc[mi][nj] = __builtin_amdgcn_mfma_f32_16x16x32_bf16(a[mi], bfr[cc][nj], acc[mi][nj], 0, 0, 0);
    }

    __syncthreads();

    if (BNG) {
        ushort* tile = (ushort*)smem;
#pragma unroll
        for (int nj = 0; nj < 2; ++nj) {
            const int n = n_wave + nj * 16 + lc;
            const float s = gamma[n] * rsqrtf(1.0f + 1e-5f);
            const float bb = beta[n];
#pragma unroll
            for (int mi = 0; mi < 2; ++mi)
#pragma unroll
                for (int r = 0; r < 4; ++r) {
                    const int m = m_wave + mi * 16 + lr * 4 + r;
                    float y = gelu_erf(fmaf(acc[mi][nj][r], s, bb));
                    __hip_bfloat16 h = __float2bfloat16(y);
                    tile[m * NOC + n] = *(ushort*)&h;
                }
        }
        __syncthreads();
        const int mv = min(M_BLK, OW - ow0);
        uint* dst = (uint*)((ushort*)out_ + (((size_t)b * OH + oh) * OW + ow0) * NOC);
        const uint* src = (const uint*)tile;
        for (int idx = tid; idx < mv * NOC / 2; idx += NT) dst[idx] = src[idx];
    } else {
        float* tile = (float*)smem;
#pragma unroll
        for (int nj = 0; nj < 2; ++nj) {
            const int n = n_wave + nj * 16 + lc;
#pragma unroll
            for (int mi = 0; mi < 2; ++mi)
#pragma unroll
                for (int r = 0; r < 4; ++r) {
                    const int m = m_wave + mi * 16 + lr * 4 + r;
                    tile[n * M_BLK + m] = acc[mi][nj][r];
                }
        }
        __syncthreads();
        const int mv = min(M_BLK, OW - ow0);
        float* outb = (float*)out_ + ((size_t)b * NOC * OH + oh) * OW + ow0;
        for (int idx = tid; idx < NOC * mv; idx += NT) {
            int oc = idx / mv, j = idx - oc * mv;
            outb[(size_t)oc * OH * OW + j] = tile[oc * M_BLK + j];
        }
    }
}

// ---------- implicit-GEMM MFMA conv (NHWC bf16 -> NHWC bf16), conv2/conv3 ----------
// Generalized wave tile: MI x NJ 16x16 frags per wave; kw-unrolled for load batching.
template <int M_BLK, int OC, int ICT, int NICC, int NWM, int NWN, int UNR>
__global__ __launch_bounds__(64 * NWM * NWN) void convmm_k(
    const ushort* __restrict__ in, const ushort* __restrict__ wp,
    const float* __restrict__ gamma, const float* __restrict__ beta,
    ushort* __restrict__ out,
    int IH, int IW, int OH, int OW, int NOWT)
{
    constexpr int KH = 5, KW = 15, SW = 4;
    constexpr int MI = M_BLK / (16 * NWM);
    constexpr int NJ = OC / (16 * NWN);
    constexpr int SPAN = (M_BLK - 1) * SW + KW;
    constexpr int ICB = ICT * 2;
    constexpr int NSL = ICT / 8;
    constexpr int KEYM = NSL - 1;
    constexpr int NT = 64 * NWM * NWN;
    constexpr int NUNITS = SPAN * NSL;

    __shared__ __align__(16) ushort Abuf[2][SPAN * ICT];

    int bid = blockIdx.x;
    const int owt = bid % NOWT; bid /= NOWT;
    const int oh  = bid % OH;
    const int b   = bid / OH;
    const int ow0 = owt * M_BLK;
    const int tid = threadIdx.x;
    const int w = tid >> 6, l = tid & 63;
    const int wn = w % NWN, wm = w / NWN;
    const int m_wave = wm * (16 * MI), n_wave = wn * (16 * NJ);
    const int lc = l & 15, lr = l >> 4;

    const int ih0 = oh * 2 - 2;
    const int iw0 = ow0 * SW - 2;
    const ushort* inb = in + (size_t)b * IH * IW * ICT;

    f32x4 acc[MI][NJ];
#pragma unroll
    for (int i = 0; i < MI; ++i)
#pragma unroll
        for (int j = 0; j < NJ; ++j) acc[i][j] = (f32x4){0.f, 0.f, 0.f, 0.f};

    auto stage = [&](int kh, int buf) {
        const int ih = ih0 + kh;
        char* dst = (char*)Abuf[buf];
        if ((unsigned)ih < (unsigned)IH) {
            const ushort* src = inb + (size_t)ih * IW * ICT;
            for (int u = tid; u < NUNITS; u += NT) {
                int p = u / NSL, sl = u - p * NSL;
                int iw = iw0 + p;
                uint4 v = {0u, 0u, 0u, 0u};
                if ((unsigned)iw < (unsigned)IW)
                    v = *(const uint4*)(src + (size_t)iw * ICT + sl * 8);
                *(uint4*)(dst + p * ICB + ((sl ^ ((p >> 2) & KEYM)) << 4)) = v;
            }
        } else {
            for (int u = tid; u < NUNITS; u += NT) {
                int p = u / NSL, sl = u - p * NSL;
                *(uint4*)(dst + p * ICB + ((sl ^ ((p >> 2) & KEYM)) << 4)) = (uint4){0u, 0u, 0u, 0u};
            }
        }
    };

    stage(0, 0);
#pragma unroll 1
    for (int kh = 0; kh < KH; ++kh) {
        __syncthreads();
        if (kh + 1 < KH) stage(kh + 1, (kh + 1) & 1);
        const char* buf = (const char*)Abuf[kh & 1];
        const ushort* wkh = wp + (size_t)(kh * KW) * OC * ICT + (size_t)(n_wave + lc) * ICT + lr * 8;
#pragma unroll UNR
        for (int kw = 0; kw < KW; ++kw) {
#pragma unroll
            for (int icc = 0; icc < NICC; ++icc) {
                short8_t a[MI], bf[NJ];
#pragma unroll
                for (int mi = 0; mi < MI; ++mi) {
                    const int r = m_wave + mi * 16 + lc;
                    const int p = SW * r + kw;
                    const int sl = icc * 4 + lr;
                    a[mi] = *(const short8_t*)(buf + p * ICB + ((sl ^ ((p >> 2) & KEYM)) << 4));
                }
                const ushort* wb = wkh + (size_t)kw * OC * ICT + icc * 32;
#pragma unroll
                for (int nj = 0; nj < NJ; ++nj)
                    bf[nj] = *(const short8_t*)(wb + (size_t)nj * 16 * ICT);
#pragma unroll
                for (int mi = 0; mi < MI; ++mi)
#pragma unroll
                    for (int nj = 0; nj < NJ; ++nj)
                        acc[mi][nj] = __builtin_amdgcn_mfma_f32_16x16x32_bf16(a[mi], bf[nj], acc[mi][nj], 0, 0, 0);
            }
        }
    }

    ushort* outb = out + ((size_t)b * OH + oh) * OW * OC;
#pragma unroll
    for (int nj = 0; nj < NJ; ++nj) {
        const int n = n_wave + nj * 16 + lc;
        const float s = gamma[n] * rsqrtf(1.0f + 1e-5f);
        const float bb = beta[n];
#pragma unroll
        for (int mi = 0; mi < MI; ++mi) {
#pragma unroll
            for (int r = 0; r < 4; ++r) {
                const int m = m_wave + mi * 16 + lr * 4 + r;
                const int ow = ow0 + m;
                if (ow < OW) {
                    float y = gelu_erf(fmaf(acc[mi][nj][r], s, bb));
                    __hip_bfloat16 h = __float2bfloat16(y);
                    outb[(size_t)ow * OC + n] = *(ushort*)&h;
                }
            }
        }
    }
}

// ---------- conv4: im2col (vectorized) + double-buffered MFMA GEMM ----------
__global__ void im2col4_k(const ushort* __restrict__ h3, ushort* __restrict__ A) {
    int idx = blockIdx.x * blockDim.x + threadIdx.x; // 1600 * 1200 uint4 units
    if (idx >= 1600 * 1200) return;
    int kp8 = idx % 1200, m = idx / 1200;
    int ic8 = kp8 & 15, kc = kp8 >> 4;
    int b = m / 25, p = m - b * 25;
    int oh = p / 5, ow = p - oh * 5;
    int kh = kc / 15, kw = kc - kh * 15;
    int ih = oh * 2 - 2 + kh, iw = ow * 4 - 2 + kw;
    uint4 v = {0u, 0u, 0u, 0u};
    if ((unsigned)ih < 10u && (unsigned)iw < 28u)
        v = *(const uint4*)&h3[((((size_t)b * 10 + ih) * 28 + iw) << 7) + ic8 * 8];
    *(uint4*)&A[(size_t)m * 9600 + kc * 128 + ic8 * 8] = v;
}

// C[1600][256] = A[1600][9600] * B[256][9600]^T. 64x64 tile, BK=64, double-buffered,
// XOR-swizzled LDS (source-swizzled staging per gfx950 global_load_lds rules).
__global__ __launch_bounds__(256) void gemm4_k(
    const ushort* __restrict__ A, const ushort* __restrict__ B,
    const float* __restrict__ gamma, const float* __restrict__ beta,
    float* __restrict__ C)
{
    __shared__ ushort Al[2][64 * 64];
    __shared__ ushort Bl[2][64 * 64];
    const int nt = blockIdx.x & 3, mt = blockIdx.x >> 2;
    const int m0 = mt * 64, n0 = nt * 64;
    const int tid = threadIdx.x;
    const int w = tid >> 6, l = tid & 63;
    const int wr = (w >> 1) * 32, wc = (w & 1) * 32;
    const int lc = l & 15, lr = l >> 4;

    f32x4 acc[2][2];
#pragma unroll
    for (int i = 0; i < 2; ++i)
#pragma unroll
        for (int j = 0; j < 2; ++j) acc[i][j] = (f32x4){0.f, 0.f, 0.f, 0.f};

    // staging: wave w covers rows [w*8 + ro*32, +8); lane l -> row w*8+l/8, swizzled col
    const int srow = w * 8 + (l >> 3);
    const int scol = ((l & 7) ^ ((l >> 3) & 7)) * 8;   // pre-swizzled source col (8-elem units)
    const ushort* ga = A + (size_t)(m0 + srow) * 9600 + scol;
    const ushort* gb = B + (size_t)(n0 + srow) * 9600 + scol;

    auto stage = [&](int buf, int kc) {
#pragma unroll
        for (int ro = 0; ro < 2; ++ro) {
            __builtin_amdgcn_global_load_lds(ga + (size_t)ro * 32 * 9600 + kc * 64,
                                             &Al[buf][(ro * 32 + w * 8) * 64], 16, 0, 0);
            __builtin_amdgcn_global_load_lds(gb + (size_t)ro * 32 * 9600 + kc * 64,
                                             &Bl[buf][(ro * 32 + w * 8) * 64], 16, 0, 0);
        }
    };

    stage(0, 0);
    asm volatile("s_waitcnt vmcnt(0)");
    __syncthreads();

    for (int kc = 0; kc < 150; ++kc) {
        const int cur = kc & 1;
        if (kc + 1 < 150) stage(cur ^ 1, kc + 1);
        short8_t a[2][2], bq[2][2];   // [mi|nj][ks]
#pragma unroll
        for (int mi = 0; mi < 2; ++mi)
#pragma unroll
            for (int ks = 0; ks < 2; ++ks) {
                const int row = wr + mi * 16 + lc;
                const int sl = (ks * 4 + lr) ^ (lc & 7);
                a[mi][ks] = *(const short8_t*)&Al[cur][row * 64 + sl * 8];
            }
#pragma unroll
        for (int nj = 0; nj < 2; ++nj)
#pragma unroll
            for (int ks = 0; ks < 2; ++ks) {
                const int row = wc + nj * 16 + lc;
                const int sl = (ks * 4 + lr) ^ (lc & 7);
                bq[nj][ks] = *(const short8_t*)&Bl[cur][row * 64 + sl * 8];
            }
#pragma unroll
        for (int ks = 0; ks < 2; ++ks)
#pragma unroll
            for (int mi = 0; mi < 2; ++mi)
#pragma unroll
                for (int nj = 0; nj < 2; ++nj)
                    acc[mi][nj] = __builtin_amdgcn_mfma_f32_16x16x32_bf16(a[mi][ks], bq[nj][ks], acc[mi][nj], 0, 0, 0);
        asm volatile("s_waitcnt vmcnt(0) lgkmcnt(0)");
        __syncthreads();
    }

#pragma unroll
    for (int mi = 0; mi < 2; ++mi)
#pragma unroll
        for (int nj = 0; nj < 2; ++nj) {
            const int n = n0 + wc + 16 * nj + lc;
            const float s = gamma[n] * rsqrtf(1.0f + 1e-5f);
            const float bb = beta[n];
#pragma unroll
            for (int r = 0; r < 4; ++r) {
                const int m = m0 + wr + 16 * mi + 4 * lr + r;
                C[(size_t)m * 256 + n] = gelu_erf(fmaf(acc[mi][nj][r], s, bb));
            }
        }
}

// ---------- routing head ----------
__global__ void route_k(const float* __restrict__ h4t,
                        const float* __restrict__ fw1, const float* __restrict__ fb1,
                        const float* __restrict__ g1d, const float* __restrict__ b1d,
                        const float* __restrict__ fw2, const float* __restrict__ fb2,
                        float* __restrict__ rw_out, int* __restrict__ sel_out)
{
    __shared__ float pooled[256];
    __shared__ float hmid[32];
    __shared__ float rwv[5];
    const int b = blockIdx.x, c = threadIdx.x;
    const float* p = h4t + (size_t)b * 25 * 256 + c;
    float sum = 0.f;
#pragma unroll
    for (int i = 0; i < 25; ++i) sum += p[i * 256];
    pooled[c] = sum * (1.0f / 25.0f);
    __syncthreads();
    if (c < 32) {
        float a = fb1[c];
        const float* wr = fw1 + c * 256;
        for (int i = 0; i < 256; ++i) a += pooled[i] * wr[i];
        a = gelu_erf(a);
        a = a * (g1d[c] * rsqrtf(1.0f + 1e-5f)) + b1d[c];
        hmid[c] = a;
    }
    __syncthreads();
    if (c < 5) {
        float a = fb2[c];
        const float* wr = fw2 + c * 32;
#pragma unroll
        for (int i = 0; i < 32; ++i) a += hmid[i] * wr[i];
        rwv[c] = a;
        rw_out[b * 5 + c] = a;
    }
    __syncthreads();
    if (c == 0) {
        int i1 = 0;
        for (int i = 1; i < 5; ++i) if (rwv[i] > rwv[i1]) i1 = i;
        int i2 = -1;
        for (int i = 0; i < 5; ++i) {
            if (i == i1) continue;
            if (i2 < 0 || rwv[i] > rwv[i2]) i2 = i;
        }
        sel_out[b * 2]     = i1 < i2 ? i1 : i2;
        sel_out[b * 2 + 1] = i1 < i2 ? i2 : i1;
    }
}

// gather -> packed bf16 pairs
__global__ void gather_k(const float* __restrict__ x, const int* __restrict__ sel,
                         uint* __restrict__ gated)
{
    const int idx = blockIdx.x * blockDim.x + threadIdx.x; // B*80*400
    const int b = idx / 32000;
    const int s0 = sel[b * 2], s1 = sel[b * 2 + 1];
    const float* xp = x + (size_t)idx * 5;
    __hip_bfloat16 h0 = __float2bfloat16(xp[s0]);
    __hip_bfloat16 h1 = __float2bfloat16(xp[s1]);
    gated[idx] = (uint)*(ushort*)&h0 | ((uint)*(ushort*)&h1 << 16);
}

extern "C" void kernel_launch(void* const* d_in, const int* in_sizes, int n_in,
                              void* d_out, int out_size, void* d_ws, size_t ws_size,
                              hipStream_t stream)
{
    const float* x     = (const float*)d_in[0];
    const float* total = (const float*)d_in[1];
    const float* gw1 = (const float*)d_in[2];
    const float* g1  = (const float*)d_in[3];
    const float* b1  = (const float*)d_in[4];
    const float* gw2 = (const float*)d_in[5];
    const float* g2  = (const float*)d_in[6];
    const float* b2  = (const float*)d_in[7];
    const float* gw3 = (const float*)d_in[8];
    const float* g3  = (const float*)d_in[9];
    const float* b3  = (const float*)d_in[10];
    const float* gw4 = (const float*)d_in[11];
    const float* g4  = (const float*)d_in[12];
    const float* b4  = (const float*)d_in[13];
    const float* fw1 = (const float*)d_in[14];
    const float* fb1 = (const float*)d_in[15];
    const float* g1d = (const float*)d_in[16];
    const float* b1d = (const float*)d_in[17];
    const float* fw2 = (const float*)d_in[18];
    const float* fb2 = (const float*)d_in[19];
    const float* cw1 = (const float*)d_in[20];

    char* ws = (char*)d_ws;
    size_t off = 0;
    auto alloc = [&](size_t bytes) { void* p = ws + off; off = (off + bytes + 255) & ~(size_t)255; return p; };
    ushort* h1n = (ushort*)alloc((size_t)40796160 * 2); // NHWC [64][40][498][32]
    ushort* h2n = (ushort*)alloc((size_t)9994240 * 2);  // NHWC [64][20][122][64]
    ushort* h3n = (ushort*)alloc((size_t)2293760 * 2);  // NHWC [64][10][28][128]
    float* h4t   = (float*)alloc((size_t)409600 * 4);   // [1600][256]
    int*   sel   = (int*)alloc(512);
    uint*  gated = (uint*)alloc((size_t)2048000 * 4);   // [64][80][400] packed bf16x2
    ushort* wp1 = (ushort*)alloc((size_t)32 * 96 * 2);
    ushort* wp2 = (ushort*)alloc((size_t)153600 * 2);   // [75][64][32]
    ushort* wp3 = (ushort*)alloc((size_t)614400 * 2);   // [75][128][64]
    ushort* wp5 = (ushort*)alloc((size_t)64 * 128 * 2);
    ushort* A4  = (ushort*)h1n;  // 30.7MB <= 81.6MB; h1 dead after conv2
    ushort* w4p = (ushort*)h2n;  // 4.9MB  <= 20MB;   h2 dead after conv3

    float* outc = (float*)d_out;            // [64,64,40,397]
    float* rw   = outc + (size_t)65044480;  // [64,5]

    // weight prep
    wperm1_k<<<(32 * 96 + 255) / 256, 256, 0, stream>>>(gw1, wp1);
    wperm5_k<<<(64 * 128 + 255) / 256, 256, 0, stream>>>(cw1, wp5);
    wperm_k<<<(153600 + 255) / 256, 256, 0, stream>>>(gw2, wp2, 64, 32, 75);
    wperm_k<<<(614400 + 255) / 256, 256, 0, stream>>>(gw3, wp3, 128, 64, 75);

    // L1: MFMA IC=1 conv.
    convmm1_k<128, 32, 3, 4, 1, 4, true, true><<<64 * 40 * 4, 256, 0, stream>>>(
        total, wp1, g1, b1, h1n, 80, 2000, 40, 498, 4, 2);

    // L2: full-row tile M_BLK=128 (OW=122), waves 2x2 of 64m x 32n, kw-unroll 5.
    convmm_k<128, 64, 32, 1, 2, 2, 5><<<64 * 20, 256, 0, stream>>>(
        h1n, wp2, g2, b2, h2n, 40, 498, 20, 122, 1);

    // L3: M_BLK=32 (OW=28), OC=128, IC=64 (2 chunks), waves 1x4, kw-unroll 5.
    convmm_k<32, 128, 64, 2, 1, 4, 5><<<64 * 10, 256, 0, stream>>>(
        h2n, wp3, g3, b3, h3n, 20, 122, 10, 28, 1);

    // L4: im2col + double-buffered MFMA GEMM
    wperm4_k<<<(2457600 + 255) / 256, 256, 0, stream>>>(gw4, w4p);
    im2col4_k<<<(1600 * 1200 + 255) / 256, 256, 0, stream>>>(h3n, A4);
    gemm4_k<<<100, 256, 0, stream>>>(A4, w4p, g4, b4, h4t);

    route_k<<<64, 256, 0, stream>>>(h4t, fw1, fb1, g1d, b1d, fw2, fb2, rw, sel);
    gather_k<<<8000, 256, 0, stream>>>(x, sel, gated);

    // L5: MFMA IC=1 conv via (t,s) factorization.
    convmm1_k<64, 64, 4, 2, 2, 2, false, false><<<64 * 40 * 7, 256, 0, stream>>>(
        gated, wp5, nullptr, nullptr, outc, 80, 400, 40, 397, 7, 3);
}